// Round 1
// baseline (453.275 us; speedup 1.0000x reference)
//
#include <hip/hip_runtime.h>
#include <hip/hip_bf16.h>
#include <hip/hip_fp8.h>

#define O_NODES 50000
#define N_EDGES 200000
#define DD 256

typedef float f32x4 __attribute__((ext_vector_type(4)));

// ---------- fp8 e4m3 helpers ----------
__device__ __forceinline__ unsigned pack4_fp8(float a, float b, float c, float d) {
#if __has_builtin(__builtin_amdgcn_cvt_pk_fp8_f32)
    int v = __builtin_amdgcn_cvt_pk_fp8_f32(a, b, 0, false);
    v = __builtin_amdgcn_cvt_pk_fp8_f32(c, d, v, true);
    return (unsigned)v;
#else
    __hip_fp8_e4m3 x(a), y(b), z(c), w(d);
    return (unsigned)x.__x | ((unsigned)y.__x << 8) | ((unsigned)z.__x << 16) | ((unsigned)w.__x << 24);
#endif
}

__device__ __forceinline__ unsigned char f2fp8(float x) {
#if __has_builtin(__builtin_amdgcn_cvt_pk_fp8_f32)
    return (unsigned char)(__builtin_amdgcn_cvt_pk_fp8_f32(x, x, 0, false) & 0xff);
#else
    __hip_fp8_e4m3 t(x); return t.__x;
#endif
}

__device__ __forceinline__ f32x4 unpack4_fp8(unsigned v) {
#if __has_builtin(__builtin_amdgcn_cvt_pk_f32_fp8)
    auto lo = __builtin_amdgcn_cvt_pk_f32_fp8((int)v, false);
    auto hi = __builtin_amdgcn_cvt_pk_f32_fp8((int)v, true);
    return (f32x4){lo[0], lo[1], hi[0], hi[1]};
#else
    __hip_fp8_e4m3 t0, t1, t2, t3;
    t0.__x = v & 0xff; t1.__x = (v >> 8) & 0xff; t2.__x = (v >> 16) & 0xff; t3.__x = (v >> 24) & 0xff;
    return (f32x4){(float)t0, (float)t1, (float)t2, (float)t3};
#endif
}

__device__ __forceinline__ f32x4 mfma_fp8(long a, long b, f32x4 c) {
    return __builtin_amdgcn_mfma_f32_16x16x32_fp8_fp8(a, b, c, 0, 0, 0);
}

// ---------- generic input helpers ----------
__device__ __forceinline__ int get_pair(const int* __restrict__ p, long e, int which, int is32) {
    return is32 ? p[2 * e + which] : p[4 * e + 2 * which];
}

__device__ __forceinline__ float load_f(const void* p, long i, int is_f32) {
    if (is_f32) return ((const float*)p)[i];
    unsigned short u = ((const unsigned short*)p)[i];
    return __uint_as_float((unsigned)u << 16);
}

__device__ __forceinline__ float bf2f(unsigned short u) {
    return __uint_as_float((unsigned)u << 16);
}

__device__ __forceinline__ unsigned short f2bf(float x) {
    __hip_bfloat16 h = __float2bfloat16(x);
    return *(unsigned short*)&h;
}

// wave-collective dtype probes (call with full wave active, before any divergence)
__device__ __forceinline__ int detect_is32_w(const int* __restrict__ pairs) {
    int lane = threadIdx.x & 63;
    unsigned long long m = __ballot(pairs[2 * lane + 1] != 0);  // int64 high words all 0
    return m != 0ull;
}
__device__ __forceinline__ int detect_isf_w(const unsigned short* __restrict__ w) {
    int lane = threadIdx.x & 63;
    unsigned short u = w[2 * lane];
    float v = fabsf(__uint_as_float((unsigned)u << 16));
    unsigned long long m = __ballot(v > 0.004f && v < 16.0f);
    return (__popcll(m) < 32) ? 1 : 0;   // low halves mostly out-of-range => f32
}

// ---------- mega setup: cvt_objf | pack W1cat+W2cat | edge max+count | flag ----------
// W1cat pack, fp8, [K=256][N=1024], N-concat: n<512 -> W1[k][n]; n>=512 -> W1[256+k][n-512].
//   byte idx: j=idx&7, half=(idx>>3)&1, lane=(idx>>4)&63, p=(idx>>10)&31, tk=idx>>15
//   holds Wc[k = tk*32+(lane>>4)*8+j][n = (2p+half)*16+(lane&15)]
//   -> ulonglong2 at [(tk*32+p)*64+lane] = B-frags for n-tiles (2p, 2p+1).
// W2cat pack, fp8, [K=1024][N=256], K-concat: k<512 -> W2[k][n]; k>=512 -> W2[k-512][256+n].
//   byte idx: j=idx&7, half=(idx>>3)&1, lane=(idx>>4)&63, p=(idx>>10)&7, tk=idx>>13
//   -> ulonglong2 at [(kt*8+p)*64+lane].
#define MEGA_A 12500
#define MEGA_B 2048
#define MEGA_C 782
__global__ __launch_bounds__(256) void mega_setup(
    const void* __restrict__ objf, const int* __restrict__ pairs, const void* __restrict__ conf,
    const void* __restrict__ W1, const void* __restrict__ W2,
    unsigned* __restrict__ objf8, unsigned char* __restrict__ w1p, unsigned char* __restrict__ w2p,
    float* __restrict__ mbuf, int* __restrict__ count, int* __restrict__ flag)
{
    int b = blockIdx.x, t = threadIdx.x;
    if (b < MEGA_A) {
        int isf = detect_isf_w((const unsigned short*)objf);
        int i4 = b * 256 + t;
        float x0, x1, x2, x3;
        if (isf) {
            float4 v = ((const float4*)objf)[i4];
            x0 = v.x; x1 = v.y; x2 = v.z; x3 = v.w;
        } else {
            ushort4 u = ((const ushort4*)objf)[i4];
            x0 = bf2f(u.x); x1 = bf2f(u.y); x2 = bf2f(u.z); x3 = bf2f(u.w);
        }
        objf8[i4] = pack4_fp8(x0, x1, x2, x3);
    } else if (b < MEGA_A + MEGA_B) {
        int isf = detect_isf_w((const unsigned short*)objf);
        int bb = b - MEGA_A;
        int idx = ((bb & 1023) << 8) + t;
        if (bb < 1024) {   // W1cat [256][1024]
            int j = idx & 7, half = (idx >> 3) & 1, lane = (idx >> 4) & 63;
            int p = (idx >> 10) & 31, tk = idx >> 15;
            int k = tk * 32 + (lane >> 4) * 8 + j;
            int n = (2 * p + half) * 16 + (lane & 15);
            long src = (n < 512) ? ((long)k * 512 + n) : ((long)(256 + k) * 512 + (n - 512));
            w1p[idx] = f2fp8(load_f(W1, src, isf));
        } else {           // W2cat [1024][256]
            int j = idx & 7, half = (idx >> 3) & 1, lane = (idx >> 4) & 63;
            int p = (idx >> 10) & 7, tk = idx >> 13;
            int k = tk * 32 + (lane >> 4) * 8 + j;
            int n = (2 * p + half) * 16 + (lane & 15);
            long src = (k < 512) ? ((long)k * 512 + n) : ((long)(k - 512) * 512 + 256 + n);
            w2p[idx] = f2fp8(load_f(W2, src, isf));
        }
    } else if (b < MEGA_A + MEGA_B + MEGA_C) {
        int is32 = detect_is32_w(pairs);
        int isf  = detect_isf_w((const unsigned short*)objf);
        int i = (b - MEGA_A - MEGA_B) * 256 + t;
        if (i >= N_EDGES) return;
        int s = get_pair(pairs, i, 0, is32);
        int o = get_pair(pairs, i, 1, is32);
        float c = load_f(conf, i, isf);
        int cb = __float_as_int(c);
        // mbuf memset 0; mbuf = max(0, max conf) — any shift point m works since we
        // rescale by S = exp(mbuf - max(mbuf,10)) in the epilogue (exact identity).
        atomicMax((int*)&mbuf[s], cb);
        atomicMax((int*)&mbuf[o], cb);
        atomicAdd(&count[s], 1);
        atomicAdd(&count[o], 1);
    } else {
        int is32 = detect_is32_w(pairs);
        int isf  = detect_isf_w((const unsigned short*)objf);
        if (t == 0) { flag[0] = is32; flag[1] = isf; }
    }
}

// coalesced single-block scan
#define SCAN_T 1024
__global__ __launch_bounds__(SCAN_T) void scan50k(const int* __restrict__ count,
                                                  int* __restrict__ offsets,
                                                  int* __restrict__ cursor) {
    __shared__ int wsum[16];
    __shared__ int carry_s;
    int t = threadIdx.x;
    int lane = t & 63, wid = t >> 6;
    if (t == 0) carry_s = 0;
    __syncthreads();
    for (int base = 0; base < O_NODES; base += SCAN_T) {
        int i = base + t;
        int c = (i < O_NODES) ? count[i] : 0;
        int v = c;
        #pragma unroll
        for (int d = 1; d < 64; d <<= 1) {
            int u = __shfl_up(v, d, 64);
            if (lane >= d) v += u;
        }
        if (lane == 63) wsum[wid] = v;
        __syncthreads();
        if (wid == 0) {
            int s = (lane < 16) ? wsum[lane] : 0;
            #pragma unroll
            for (int d = 1; d < 16; d <<= 1) {
                int u = __shfl_up(s, d, 64);
                if (lane >= d) s += u;
            }
            if (lane < 16) wsum[lane] = s;
        }
        __syncthreads();
        int wprefix = (wid == 0) ? 0 : wsum[wid - 1];
        int excl = carry_s + wprefix + v - c;
        if (i < O_NODES) { offsets[i] = excl; cursor[i] = excl; }
        int total = wsum[15];
        __syncthreads();
        if (t == 0) carry_s += total;
        __syncthreads();
    }
}

__global__ void scatter_inc(const int* __restrict__ pairs, int* __restrict__ cursor,
                            int* __restrict__ inc, const int* __restrict__ flag) {
    int i = blockIdx.x * 256 + threadIdx.x;
    if (i >= N_EDGES) return;
    int is32 = flag[0];
    int s = get_pair(pairs, i, 0, is32);
    int o = get_pair(pairs, i, 1, is32);
    int ps = atomicAdd(&cursor[s], 1);
    inc[ps] = 2 * i;
    int po = atomicAdd(&cursor[o], 1);
    inc[po] = 2 * i + 1;
}

// ---------- node-level GEMM1: P[50k][1024] fp8 = objf8[50k][256] @ W1cat[256][1024] ----------
// grid = 782*2: mb = blockIdx>>1 (64 rows), nh = blockIdx&1 (512-col half).
// A staged in two frag-major regions (m-tiles {0,1},{2,3}), 8 tk of K=32:
//   region h byte addr = h*8192 + (tk*64 + lane)*16 + mt'*8 + j
//   holds A[m=(h*2+mt')*16+(lane&15)][k=tk*32+(lane>>4)*8+j]
__global__ __launch_bounds__(512, 4) void gemm1_node(
    const unsigned* __restrict__ objf8,
    const unsigned char* __restrict__ w1p,
    unsigned char* __restrict__ P)
{
    extern __shared__ char smem[];
    unsigned char* sA = (unsigned char*)smem;    // frag: 16KB; epi: 64x528 = 33792

    const int tid  = threadIdx.x;
    const int wave = tid >> 6;
    const int lane = tid & 63;
    const int l15  = lane & 15;
    const int lq   = lane >> 4;
    const int mb   = blockIdx.x >> 1;
    const int nh   = blockIdx.x & 1;
    const long bs  = (long)mb * 64;

    // stage A: 64 rows x 32 k-octets = 2048 uint2; 4 per thread
    #pragma unroll
    for (int it = 0; it < 4; ++it) {
        int q   = it * 512 + tid;
        int m15 = q & 15;
        int mtp = (q >> 4) & 1;
        int h   = (q >> 5) & 1;
        int lqk = (q >> 6) & 3;
        int tk  = (q >> 8) & 7;
        int m   = (h * 2 + mtp) * 16 + m15;
        long node = bs + m; if (node >= O_NODES) node = O_NODES - 1;
        uint2 v = *(const uint2*)(objf8 + node * 64 + tk * 8 + lqk * 2);
        *(uint2*)(sA + h * 8192 + (tk * 64 + lqk * 16 + m15) * 16 + mtp * 8) = v;
    }
    __syncthreads();

    f32x4 acc[4][4];
    #pragma unroll
    for (int mt = 0; mt < 4; ++mt)
        #pragma unroll
        for (int nt = 0; nt < 4; ++nt)
            acc[mt][nt] = (f32x4){0.f, 0.f, 0.f, 0.f};

    {
        const ulonglong2* bq = (const ulonglong2*)w1p;
        const int pbase = nh * 16 + wave * 2;
        #pragma unroll 2
        for (int tk = 0; tk < 8; ++tk) {
            ulonglong2 av01 = *(const ulonglong2*)(sA + tk * 1024 + lane * 16);
            ulonglong2 av23 = *(const ulonglong2*)(sA + 8192 + tk * 1024 + lane * 16);
            ulonglong2 b01  = bq[(tk * 32 + pbase) * 64 + lane];
            ulonglong2 b23  = bq[(tk * 32 + pbase + 1) * 64 + lane];
            long a0 = (long)av01.x, a1 = (long)av01.y;
            long a2 = (long)av23.x, a3 = (long)av23.y;
            acc[0][0] = mfma_fp8(a0, (long)b01.x, acc[0][0]);
            acc[1][0] = mfma_fp8(a1, (long)b01.x, acc[1][0]);
            acc[2][0] = mfma_fp8(a2, (long)b01.x, acc[2][0]);
            acc[3][0] = mfma_fp8(a3, (long)b01.x, acc[3][0]);
            acc[0][1] = mfma_fp8(a0, (long)b01.y, acc[0][1]);
            acc[1][1] = mfma_fp8(a1, (long)b01.y, acc[1][1]);
            acc[2][1] = mfma_fp8(a2, (long)b01.y, acc[2][1]);
            acc[3][1] = mfma_fp8(a3, (long)b01.y, acc[3][1]);
            acc[0][2] = mfma_fp8(a0, (long)b23.x, acc[0][2]);
            acc[1][2] = mfma_fp8(a1, (long)b23.x, acc[1][2]);
            acc[2][2] = mfma_fp8(a2, (long)b23.x, acc[2][2]);
            acc[3][2] = mfma_fp8(a3, (long)b23.x, acc[3][2]);
            acc[0][3] = mfma_fp8(a0, (long)b23.y, acc[0][3]);
            acc[1][3] = mfma_fp8(a1, (long)b23.y, acc[1][3]);
            acc[2][3] = mfma_fp8(a2, (long)b23.y, acc[2][3]);
            acc[3][3] = mfma_fp8(a3, (long)b23.y, acc[3][3]);
        }
    }
    __syncthreads();

    // fp8 row-major (stride 528) -> coalesced stream into P
    #pragma unroll
    for (int nt = 0; nt < 4; ++nt) {
        int c = wave * 64 + nt * 16 + l15;
        #pragma unroll
        for (int mt = 0; mt < 4; ++mt) {
            #pragma unroll
            for (int r = 0; r < 4; ++r) {
                sA[(mt * 16 + lq * 4 + r) * 528 + c] = f2fp8(acc[mt][nt][r]);
            }
        }
    }
    __syncthreads();
    #pragma unroll
    for (int it = 0; it < 4; ++it) {
        int idx = it * 512 + tid;
        int row = idx >> 5;
        int ch  = idx & 31;
        if (bs + row < O_NODES) {
            uint4 v = *(const uint4*)(sA + row * 528 + ch * 16);
            ((uint4*)P)[(bs + row) * 64 + nh * 32 + ch] = v;
        }
    }
}

// ---------- per-node weighted-h accumulation (one wave per node) ----------
// h_e = relu(Ptop[sub_e] + Pbot[obj_e] + b1); Hcat[n] = [ Σ_{sub} w h | Σ_{obj} w h ] fp8
// w = exp(conf - mbuf[n])  (rescaled; S reapplied in gemm2 epilogue)
__global__ __launch_bounds__(256) void node_accum(
    const unsigned* __restrict__ Pu,     // P as uints, row = 256 uints
    const int* __restrict__ pairs,
    const void* __restrict__ conf,
    const int* __restrict__ inc,
    const int* __restrict__ offsets,
    const int* __restrict__ count,
    const float* __restrict__ mbuf,
    const void* __restrict__ b1,
    unsigned char* __restrict__ Hcat,
    float* __restrict__ ws_s, float* __restrict__ ws_o,
    const int* __restrict__ flag)
{
    int nid = blockIdx.x * 4 + (threadIdx.x >> 6);
    if (nid >= O_NODES) return;
    int lane = threadIdx.x & 63;
    int is32 = flag[0], isf = flag[1];

    int off = offsets[nid];
    int deg = count[nid];
    float mm = mbuf[nid];

    uint2 vt = *(const uint2*)(Pu + (long)nid * 256 + lane * 2);
    uint2 vb = *(const uint2*)(Pu + (long)nid * 256 + 128 + lane * 2);
    f32x4 ot0 = unpack4_fp8(vt.x), ot1 = unpack4_fp8(vt.y);
    f32x4 ob0 = unpack4_fp8(vb.x), ob1 = unpack4_fp8(vb.y);
    float b1v[8];
    #pragma unroll
    for (int j = 0; j < 8; ++j) b1v[j] = load_f(b1, lane * 8 + j, isf);

    float accS[8], accO[8];
    #pragma unroll
    for (int j = 0; j < 8; ++j) { accS[j] = 0.f; accO[j] = 0.f; }
    float wS = 0.f, wO = 0.f;

    int i = 0;
    while (i < deg) {
        int nb = deg - i; if (nb > 4) nb = 4;
        uint2 pv[4]; float w[4]; int role[4];
        #pragma unroll
        for (int k = 0; k < 4; ++k) if (k < nb) {
            int jj = inc[off + i + k];
            long e = jj >> 1; role[k] = jj & 1;
            int partner = get_pair(pairs, e, role[k] ^ 1, is32);
            float c = load_f(conf, e, isf);
            w[k] = __expf(c - mm);
            pv[k] = *(const uint2*)(Pu + (long)partner * 256 + (role[k] ? 0 : 128) + lane * 2);
        }
        #pragma unroll
        for (int k = 0; k < 4; ++k) if (k < nb) {
            f32x4 p0 = unpack4_fp8(pv[k].x), p1 = unpack4_fp8(pv[k].y);
            float wk = w[k];
            if (role[k]) {   // nid is obj: h = relu(Ptop[partner] + Pbot[nid] + b1)
                wO += wk;
                #pragma unroll
                for (int j = 0; j < 4; ++j) accO[j]     += wk * fmaxf(ob0[j] + p0[j] + b1v[j], 0.f);
                #pragma unroll
                for (int j = 0; j < 4; ++j) accO[4 + j] += wk * fmaxf(ob1[j] + p1[j] + b1v[4 + j], 0.f);
            } else {         // nid is sub: h = relu(Ptop[nid] + Pbot[partner] + b1)
                wS += wk;
                #pragma unroll
                for (int j = 0; j < 4; ++j) accS[j]     += wk * fmaxf(ot0[j] + p0[j] + b1v[j], 0.f);
                #pragma unroll
                for (int j = 0; j < 4; ++j) accS[4 + j] += wk * fmaxf(ot1[j] + p1[j] + b1v[4 + j], 0.f);
            }
        }
        i += nb;
    }

    uint2 hs, ho;
    hs.x = pack4_fp8(accS[0], accS[1], accS[2], accS[3]);
    hs.y = pack4_fp8(accS[4], accS[5], accS[6], accS[7]);
    ho.x = pack4_fp8(accO[0], accO[1], accO[2], accO[3]);
    ho.y = pack4_fp8(accO[4], accO[5], accO[6], accO[7]);
    ((uint2*)Hcat)[(long)nid * 128 + lane]      = hs;
    ((uint2*)Hcat)[(long)nid * 128 + 64 + lane] = ho;
    if (lane == 0) { ws_s[nid] = wS; ws_o[nid] = wO; }
}

// ---------- node-level GEMM2 + fused finalize ----------
// out[n][c] = ( S*(Hcat[n]@W2cat + wsS*b2[c] + wsO*b2[256+c]) + selfw*objf[n][c] ) / denom
// S = exp(mm - max(mm,10)); selfw = exp(10 - max(mm,10)); denom = S*(wsS+wsO) + selfw
__global__ __launch_bounds__(512, 4) void gemm2_node(
    const unsigned* __restrict__ Hcat,
    const unsigned char* __restrict__ w2p,
    const float* __restrict__ mbuf,
    const float* __restrict__ ws_s, const float* __restrict__ ws_o,
    const void* __restrict__ objf, const void* __restrict__ b2,
    void* __restrict__ out, const int* __restrict__ flag)
{
    extern __shared__ char smem[];
    unsigned char* sA = (unsigned char*)smem;     // 32KB frags
    float* sS    = (float*)(smem + 32768);        // [64] each
    float* sSelf = sS + 64;
    float* sInv  = sS + 128;
    float* sWs   = sS + 192;
    float* sWo   = sS + 256;

    const int tid  = threadIdx.x;
    const int wave = tid >> 6;
    const int lane = tid & 63;
    const int l15  = lane & 15;
    const int lq   = lane >> 4;
    const long bs  = (long)blockIdx.x * 64;
    const int isf  = flag[1];

    if (tid < 64) {
        long node = bs + tid; if (node >= O_NODES) node = O_NODES - 1;
        float mm = mbuf[node];
        float mn = fmaxf(mm, 10.0f);
        float S     = __expf(mm - mn);
        float selfw = __expf(10.0f - mn);
        float wss = ws_s[node], wso = ws_o[node];
        sS[tid] = S; sSelf[tid] = selfw; sWs[tid] = wss; sWo[tid] = wso;
        sInv[tid] = 1.0f / (S * (wss + wso) + selfw);
    }

    f32x4 acc[4][2];
    #pragma unroll
    for (int mt = 0; mt < 4; ++mt)
        #pragma unroll
        for (int nt = 0; nt < 2; ++nt)
            acc[mt][nt] = (f32x4){0.f, 0.f, 0.f, 0.f};

    const ulonglong2* bq = (const ulonglong2*)w2p;
    #pragma unroll
    for (int kh = 0; kh < 2; ++kh) {
        // stage A half: 64 rows x 64 k-octets = 4096 uint2; 8 per thread
        #pragma unroll
        for (int it = 0; it < 8; ++it) {
            int q   = it * 512 + tid;
            int m15 = q & 15;
            int mtp = (q >> 4) & 1;
            int h   = (q >> 5) & 1;
            int lqk = (q >> 6) & 3;
            int tk  = (q >> 8) & 15;
            int m   = (h * 2 + mtp) * 16 + m15;
            long node = bs + m; if (node >= O_NODES) node = O_NODES - 1;
            uint2 v = *(const uint2*)(Hcat + node * 256 + kh * 128 + tk * 8 + lqk * 2);
            *(uint2*)(sA + h * 16384 + (tk * 64 + lqk * 16 + m15) * 16 + mtp * 8) = v;
        }
        __syncthreads();
        #pragma unroll 2
        for (int tk = 0; tk < 16; ++tk) {
            int kt = kh * 16 + tk;
            ulonglong2 av01 = *(const ulonglong2*)(sA + tk * 1024 + lane * 16);
            ulonglong2 av23 = *(const ulonglong2*)(sA + 16384 + tk * 1024 + lane * 16);
            ulonglong2 b    = bq[(kt * 8 + wave) * 64 + lane];
            long a0 = (long)av01.x, a1 = (long)av01.y;
            long a2 = (long)av23.x, a3 = (long)av23.y;
            acc[0][0] = mfma_fp8(a0, (long)b.x, acc[0][0]);
            acc[1][0] = mfma_fp8(a1, (long)b.x, acc[1][0]);
            acc[2][0] = mfma_fp8(a2, (long)b.x, acc[2][0]);
            acc[3][0] = mfma_fp8(a3, (long)b.x, acc[3][0]);
            acc[0][1] = mfma_fp8(a0, (long)b.y, acc[0][1]);
            acc[1][1] = mfma_fp8(a1, (long)b.y, acc[1][1]);
            acc[2][1] = mfma_fp8(a2, (long)b.y, acc[2][1]);
            acc[3][1] = mfma_fp8(a3, (long)b.y, acc[3][1]);
        }
        __syncthreads();
    }

    // fused finalize epilogue
    #pragma unroll
    for (int nt = 0; nt < 2; ++nt) {
        int c = wave * 32 + nt * 16 + l15;
        float b2c = load_f(b2, c, isf);
        float b2d = load_f(b2, 256 + c, isf);
        #pragma unroll
        for (int mt = 0; mt < 4; ++mt) {
            #pragma unroll
            for (int r = 0; r < 4; ++r) {
                int row = mt * 16 + lq * 4 + r;
                long node = bs + row;
                if (node < O_NODES) {
                    float o = load_f(objf, node * 256 + c, isf);
                    float val = (sS[row] * (acc[mt][nt][r] + sWs[row] * b2c + sWo[row] * b2d)
                                 + sSelf[row] * o) * sInv[row];
                    if (isf) ((float*)out)[node * 256 + c] = val;
                    else     ((unsigned short*)out)[node * 256 + c] = f2bf(val);
                }
            }
        }
    }
}

extern "C" void kernel_launch(void* const* d_in, const int* in_sizes, int n_in,
                              void* d_out, int out_size, void* d_ws, size_t ws_size,
                              hipStream_t stream) {
    const void* objf  = d_in[0];
    const int*  pairs = (const int*)d_in[1];
    const void* conf  = d_in[2];
    const void* W1    = d_in[3];
    const void* b1    = d_in[4];
    const void* W2    = d_in[5];
    const void* b2    = d_in[6];

    char* ws = (char*)d_ws;
    // layout (bytes):
    //   0        count   200000
    //   200000   mbuf    200000
    //   400000   flag    64
    //   400064   offsets 200000
    //   600064   cursor  200000
    //   800064   inc     1600000
    //   2400064  w1p     262144
    //   2662208  w2p     262144
    //   2924352  ws_s    200000
    //   3124352  ws_o    200000
    //   3324352  P       51200000   (fp8 [50k][1024])
    //   54524352 objf8   12800000   (dead after gemm1_node)
    //   54524352 Hcat    51200000   (overlays objf8; written by node_accum)
    //   total need = 105,724,352  (< 118.1 MB proven available by prior CSR run)
    int*   count   = (int*)  ws;
    float* mbuf    = (float*)(ws + 200000);
    int*   flag    = (int*)  (ws + 400000);
    int*   offsets = (int*)  (ws + 400064);
    int*   cursor  = (int*)  (ws + 600064);
    int*   inc     = (int*)  (ws + 800064);
    unsigned char* w1p = (unsigned char*)(ws + 2400064);
    unsigned char* w2p = (unsigned char*)(ws + 2662208);
    float* wss     = (float*)(ws + 2924352);
    float* wso     = (float*)(ws + 3124352);
    unsigned char* P    = (unsigned char*)(ws + 3324352);
    unsigned*      objf8 = (unsigned*)(ws + 54524352);
    unsigned char* Hcat  = (unsigned char*)(ws + 54524352);

    hipMemsetAsync(count, 0, 400064, stream);   // count + mbuf(0) + flag

    mega_setup<<<MEGA_A + MEGA_B + MEGA_C + 1, 256, 0, stream>>>(
        objf, pairs, conf, W1, W2, objf8, w1p, w2p, mbuf, count, flag);

    scan50k<<<1, SCAN_T, 0, stream>>>(count, offsets, cursor);
    scatter_inc<<<(N_EDGES + 255) / 256, 256, 0, stream>>>(pairs, cursor, inc, flag);

    gemm1_node<<<2 * ((O_NODES + 63) / 64), 512, 33792, stream>>>(objf8, w1p, P);

    node_accum<<<(O_NODES + 3) / 4, 256, 0, stream>>>(
        (const unsigned*)P, pairs, conf, inc, offsets, count, mbuf, b1, Hcat, wss, wso, flag);

    gemm2_node<<<(O_NODES + 63) / 64, 512, 34048, stream>>>(
        (const unsigned*)Hcat, w2p, mbuf, wss, wso, objf, b2, d_out, flag);
}

// Round 2
// 387.446 us; speedup vs baseline: 1.1699x; 1.1699x over previous
//
#include <hip/hip_runtime.h>
#include <hip/hip_bf16.h>
#include <hip/hip_fp8.h>

#define O_NODES 50000
#define N_EDGES 200000
#define DD 256

typedef float f32x4 __attribute__((ext_vector_type(4)));

// ---------- fp8 e4m3 helpers ----------
__device__ __forceinline__ unsigned pack4_fp8(float a, float b, float c, float d) {
#if __has_builtin(__builtin_amdgcn_cvt_pk_fp8_f32)
    int v = __builtin_amdgcn_cvt_pk_fp8_f32(a, b, 0, false);
    v = __builtin_amdgcn_cvt_pk_fp8_f32(c, d, v, true);
    return (unsigned)v;
#else
    __hip_fp8_e4m3 x(a), y(b), z(c), w(d);
    return (unsigned)x.__x | ((unsigned)y.__x << 8) | ((unsigned)z.__x << 16) | ((unsigned)w.__x << 24);
#endif
}

__device__ __forceinline__ unsigned char f2fp8(float x) {
#if __has_builtin(__builtin_amdgcn_cvt_pk_fp8_f32)
    return (unsigned char)(__builtin_amdgcn_cvt_pk_fp8_f32(x, x, 0, false) & 0xff);
#else
    __hip_fp8_e4m3 t(x); return t.__x;
#endif
}

__device__ __forceinline__ f32x4 unpack4_fp8(unsigned v) {
#if __has_builtin(__builtin_amdgcn_cvt_pk_f32_fp8)
    auto lo = __builtin_amdgcn_cvt_pk_f32_fp8((int)v, false);
    auto hi = __builtin_amdgcn_cvt_pk_f32_fp8((int)v, true);
    return (f32x4){lo[0], lo[1], hi[0], hi[1]};
#else
    __hip_fp8_e4m3 t0, t1, t2, t3;
    t0.__x = v & 0xff; t1.__x = (v >> 8) & 0xff; t2.__x = (v >> 16) & 0xff; t3.__x = (v >> 24) & 0xff;
    return (f32x4){(float)t0, (float)t1, (float)t2, (float)t3};
#endif
}

__device__ __forceinline__ f32x4 mfma_fp8(long a, long b, f32x4 c) {
    return __builtin_amdgcn_mfma_f32_16x16x32_fp8_fp8(a, b, c, 0, 0, 0);
}

// ---------- generic input helpers ----------
__device__ __forceinline__ int get_pair(const int* __restrict__ p, long e, int which, int is32) {
    return is32 ? p[2 * e + which] : p[4 * e + 2 * which];
}

__device__ __forceinline__ float load_f(const void* p, long i, int is_f32) {
    if (is_f32) return ((const float*)p)[i];
    unsigned short u = ((const unsigned short*)p)[i];
    return __uint_as_float((unsigned)u << 16);
}

__device__ __forceinline__ float bf2f(unsigned short u) {
    return __uint_as_float((unsigned)u << 16);
}

__device__ __forceinline__ unsigned short f2bf(float x) {
    __hip_bfloat16 h = __float2bfloat16(x);
    return *(unsigned short*)&h;
}

// wave-collective dtype probes (call with full wave active, before any divergence)
__device__ __forceinline__ int detect_is32_w(const int* __restrict__ pairs) {
    int lane = threadIdx.x & 63;
    unsigned long long m = __ballot(pairs[2 * lane + 1] != 0);  // int64 high words all 0
    return m != 0ull;
}
__device__ __forceinline__ int detect_isf_w(const unsigned short* __restrict__ w) {
    int lane = threadIdx.x & 63;
    unsigned short u = w[2 * lane];
    float v = fabsf(__uint_as_float((unsigned)u << 16));
    unsigned long long m = __ballot(v > 0.004f && v < 16.0f);
    return (__popcll(m) < 32) ? 1 : 0;   // low halves mostly out-of-range => f32
}

// ---------- mega setup: cvt_objf | pack W1cat+W2cat | edge max+count | flag ----------
// W1cat pack, fp8, [K=256][N=1024], N-concat: n<512 -> W1[k][n]; n>=512 -> W1[256+k][n-512].
//   byte idx: j=idx&7, half=(idx>>3)&1, lane=(idx>>4)&63, p=(idx>>10)&31, tk=idx>>15
//   holds Wc[k = tk*32+(lane>>4)*8+j][n = (2p+half)*16+(lane&15)]
//   -> ulonglong2 at [(tk*32+p)*64+lane] = B-frags for n-tiles (2p, 2p+1).
// W2cat pack, fp8, [K=1024][N=256], K-concat: k<512 -> W2[k][n]; k>=512 -> W2[k-512][256+n].
//   byte idx: j=idx&7, half=(idx>>3)&1, lane=(idx>>4)&63, p=(idx>>10)&7, tk=idx>>13
//   -> ulonglong2 at [(kt*8+p)*64+lane].
#define MEGA_A 12500
#define MEGA_B 2048
#define MEGA_C 782
__global__ __launch_bounds__(256) void mega_setup(
    const void* __restrict__ objf, const int* __restrict__ pairs, const void* __restrict__ conf,
    const void* __restrict__ W1, const void* __restrict__ W2,
    unsigned* __restrict__ objf8, unsigned char* __restrict__ w1p, unsigned char* __restrict__ w2p,
    float* __restrict__ mbuf, int* __restrict__ count, int* __restrict__ flag)
{
    int b = blockIdx.x, t = threadIdx.x;
    if (b < MEGA_A) {
        int isf = detect_isf_w((const unsigned short*)objf);
        int i4 = b * 256 + t;
        float x0, x1, x2, x3;
        if (isf) {
            float4 v = ((const float4*)objf)[i4];
            x0 = v.x; x1 = v.y; x2 = v.z; x3 = v.w;
        } else {
            ushort4 u = ((const ushort4*)objf)[i4];
            x0 = bf2f(u.x); x1 = bf2f(u.y); x2 = bf2f(u.z); x3 = bf2f(u.w);
        }
        objf8[i4] = pack4_fp8(x0, x1, x2, x3);
    } else if (b < MEGA_A + MEGA_B) {
        int isf = detect_isf_w((const unsigned short*)objf);
        int bb = b - MEGA_A;
        int idx = ((bb & 1023) << 8) + t;
        if (bb < 1024) {   // W1cat [256][1024]
            int j = idx & 7, half = (idx >> 3) & 1, lane = (idx >> 4) & 63;
            int p = (idx >> 10) & 31, tk = idx >> 15;
            int k = tk * 32 + (lane >> 4) * 8 + j;
            int n = (2 * p + half) * 16 + (lane & 15);
            long src = (n < 512) ? ((long)k * 512 + n) : ((long)(256 + k) * 512 + (n - 512));
            w1p[idx] = f2fp8(load_f(W1, src, isf));
        } else {           // W2cat [1024][256]
            int j = idx & 7, half = (idx >> 3) & 1, lane = (idx >> 4) & 63;
            int p = (idx >> 10) & 7, tk = idx >> 13;
            int k = tk * 32 + (lane >> 4) * 8 + j;
            int n = (2 * p + half) * 16 + (lane & 15);
            long src = (k < 512) ? ((long)k * 512 + n) : ((long)(k - 512) * 512 + 256 + n);
            w2p[idx] = f2fp8(load_f(W2, src, isf));
        }
    } else if (b < MEGA_A + MEGA_B + MEGA_C) {
        int is32 = detect_is32_w(pairs);
        int isf  = detect_isf_w((const unsigned short*)objf);
        int i = (b - MEGA_A - MEGA_B) * 256 + t;
        if (i >= N_EDGES) return;
        int s = get_pair(pairs, i, 0, is32);
        int o = get_pair(pairs, i, 1, is32);
        float c = load_f(conf, i, isf);
        int cb = __float_as_int(c);
        // mbuf memset 0; mbuf = max(0, max conf) — any shift point m works since we
        // rescale by S = exp(mbuf - max(mbuf,10)) in the epilogue (exact identity).
        atomicMax((int*)&mbuf[s], cb);
        atomicMax((int*)&mbuf[o], cb);
        atomicAdd(&count[s], 1);
        atomicAdd(&count[o], 1);
    } else {
        int is32 = detect_is32_w(pairs);
        int isf  = detect_isf_w((const unsigned short*)objf);
        if (t == 0) { flag[0] = is32; flag[1] = isf; }
    }
}

// coalesced single-block scan, int4 per thread (13 barrier-iterations)
#define SCAN_T 1024
__global__ __launch_bounds__(SCAN_T) void scan50k(const int* __restrict__ count,
                                                  int* __restrict__ offsets,
                                                  int* __restrict__ cursor) {
    __shared__ int wsum[16];
    __shared__ int carry_s;
    int t = threadIdx.x;
    int lane = t & 63, wid = t >> 6;
    if (t == 0) carry_s = 0;
    __syncthreads();
    for (int base = 0; base < O_NODES; base += 4 * SCAN_T) {
        int i4 = base + t * 4;
        int4 c = make_int4(0, 0, 0, 0);
        if (i4 < O_NODES) c = *(const int4*)(count + i4);   // O_NODES % 4 == 0
        int s1 = c.x, s2 = s1 + c.y, s3 = s2 + c.z, s4 = s3 + c.w;
        int v = s4;
        #pragma unroll
        for (int d = 1; d < 64; d <<= 1) {
            int u = __shfl_up(v, d, 64);
            if (lane >= d) v += u;
        }
        if (lane == 63) wsum[wid] = v;
        __syncthreads();
        if (wid == 0) {
            int s = (lane < 16) ? wsum[lane] : 0;
            #pragma unroll
            for (int d = 1; d < 16; d <<= 1) {
                int u = __shfl_up(s, d, 64);
                if (lane >= d) s += u;
            }
            if (lane < 16) wsum[lane] = s;
        }
        __syncthreads();
        int wprefix = (wid == 0) ? 0 : wsum[wid - 1];
        int excl = carry_s + wprefix + v - s4;
        if (i4 < O_NODES) {
            int4 o4 = make_int4(excl, excl + s1, excl + s2, excl + s3);
            *(int4*)(offsets + i4) = o4;
            *(int4*)(cursor + i4) = o4;
        }
        int total = wsum[15];
        __syncthreads();
        if (t == 0) carry_s += total;
        __syncthreads();
    }
}

// scatter: write full incidence records {partner<<1|role, conf_bits} — kills the
// pairs/conf dependent loads in node_accum's hot loop
__global__ void scatter_inc(const int* __restrict__ pairs, const void* __restrict__ conf,
                            int* __restrict__ cursor, int2* __restrict__ inc2,
                            const int* __restrict__ flag) {
    int i = blockIdx.x * 256 + threadIdx.x;
    if (i >= N_EDGES) return;
    int is32 = flag[0], isf = flag[1];
    int s = get_pair(pairs, i, 0, is32);
    int o = get_pair(pairs, i, 1, is32);
    int cb = __float_as_int(load_f(conf, i, isf));
    int ps = atomicAdd(&cursor[s], 1);
    inc2[ps] = make_int2((o << 1) | 0, cb);   // s is SUB of edge i, partner o
    int po = atomicAdd(&cursor[o], 1);
    inc2[po] = make_int2((s << 1) | 1, cb);   // o is OBJ of edge i, partner s
}

// ---------- node-level GEMM1: P[50k][1024] fp8 = objf8[50k][256] @ W1cat[256][1024] ----------
__global__ __launch_bounds__(512, 4) void gemm1_node(
    const unsigned* __restrict__ objf8,
    const unsigned char* __restrict__ w1p,
    unsigned char* __restrict__ P)
{
    extern __shared__ char smem[];
    unsigned char* sA = (unsigned char*)smem;    // frag: 16KB; epi: 64x528 = 33792

    const int tid  = threadIdx.x;
    const int wave = tid >> 6;
    const int lane = tid & 63;
    const int l15  = lane & 15;
    const int lq   = lane >> 4;
    const int mb   = blockIdx.x >> 1;
    const int nh   = blockIdx.x & 1;
    const long bs  = (long)mb * 64;

    // stage A: 64 rows x 32 k-octets = 2048 uint2; 4 per thread, frag-major dest
    #pragma unroll
    for (int it = 0; it < 4; ++it) {
        int q   = it * 512 + tid;
        int m15 = q & 15;
        int mtp = (q >> 4) & 1;
        int h   = (q >> 5) & 1;
        int lqk = (q >> 6) & 3;
        int tk  = (q >> 8) & 7;
        int m   = (h * 2 + mtp) * 16 + m15;
        long node = bs + m; if (node >= O_NODES) node = O_NODES - 1;
        uint2 v = *(const uint2*)(objf8 + node * 64 + tk * 8 + lqk * 2);
        *(uint2*)(sA + h * 8192 + (tk * 64 + lqk * 16 + m15) * 16 + mtp * 8) = v;
    }
    __syncthreads();

    f32x4 acc[4][4];
    #pragma unroll
    for (int mt = 0; mt < 4; ++mt)
        #pragma unroll
        for (int nt = 0; nt < 4; ++nt)
            acc[mt][nt] = (f32x4){0.f, 0.f, 0.f, 0.f};

    {
        const ulonglong2* bq = (const ulonglong2*)w1p;
        const int pbase = nh * 16 + wave * 2;
        #pragma unroll 2
        for (int tk = 0; tk < 8; ++tk) {
            ulonglong2 av01 = *(const ulonglong2*)(sA + tk * 1024 + lane * 16);
            ulonglong2 av23 = *(const ulonglong2*)(sA + 8192 + tk * 1024 + lane * 16);
            ulonglong2 b01  = bq[(tk * 32 + pbase) * 64 + lane];
            ulonglong2 b23  = bq[(tk * 32 + pbase + 1) * 64 + lane];
            long a0 = (long)av01.x, a1 = (long)av01.y;
            long a2 = (long)av23.x, a3 = (long)av23.y;
            acc[0][0] = mfma_fp8(a0, (long)b01.x, acc[0][0]);
            acc[1][0] = mfma_fp8(a1, (long)b01.x, acc[1][0]);
            acc[2][0] = mfma_fp8(a2, (long)b01.x, acc[2][0]);
            acc[3][0] = mfma_fp8(a3, (long)b01.x, acc[3][0]);
            acc[0][1] = mfma_fp8(a0, (long)b01.y, acc[0][1]);
            acc[1][1] = mfma_fp8(a1, (long)b01.y, acc[1][1]);
            acc[2][1] = mfma_fp8(a2, (long)b01.y, acc[2][1]);
            acc[3][1] = mfma_fp8(a3, (long)b01.y, acc[3][1]);
            acc[0][2] = mfma_fp8(a0, (long)b23.x, acc[0][2]);
            acc[1][2] = mfma_fp8(a1, (long)b23.x, acc[1][2]);
            acc[2][2] = mfma_fp8(a2, (long)b23.x, acc[2][2]);
            acc[3][2] = mfma_fp8(a3, (long)b23.x, acc[3][2]);
            acc[0][3] = mfma_fp8(a0, (long)b23.y, acc[0][3]);
            acc[1][3] = mfma_fp8(a1, (long)b23.y, acc[1][3]);
            acc[2][3] = mfma_fp8(a2, (long)b23.y, acc[2][3]);
            acc[3][3] = mfma_fp8(a3, (long)b23.y, acc[3][3]);
        }
    }
    __syncthreads();

    // fp8 row-major (stride 528) -> coalesced stream into P
    #pragma unroll
    for (int nt = 0; nt < 4; ++nt) {
        int c = wave * 64 + nt * 16 + l15;
        #pragma unroll
        for (int mt = 0; mt < 4; ++mt) {
            #pragma unroll
            for (int r = 0; r < 4; ++r) {
                sA[(mt * 16 + lq * 4 + r) * 528 + c] = f2fp8(acc[mt][nt][r]);
            }
        }
    }
    __syncthreads();
    #pragma unroll
    for (int it = 0; it < 4; ++it) {
        int idx = it * 512 + tid;
        int row = idx >> 5;
        int ch  = idx & 31;
        if (bs + row < O_NODES) {
            uint4 v = *(const uint4*)(sA + row * 528 + ch * 16);
            ((uint4*)P)[(bs + row) * 64 + nh * 32 + ch] = v;
        }
    }
}

// ---------- per-node weighted-h accumulation (one wave per node) ----------
// h_e = relu(Ptop[sub_e] + Pbot[obj_e] + b1); Hcat[n] = [ Σ_{sub} w h | Σ_{obj} w h ] fp8
// Lane-parallel record loads + batch-8 pipelined 512B partner reads (chain depth 2).
__global__ __launch_bounds__(256) void node_accum(
    const unsigned* __restrict__ Pu,     // P as uints, row = 256 uints
    const int2* __restrict__ inc2,
    const int* __restrict__ offsets,
    const int* __restrict__ count,
    const float* __restrict__ mbuf,
    const void* __restrict__ b1,
    unsigned char* __restrict__ Hcat,
    float* __restrict__ ws_s, float* __restrict__ ws_o,
    const int* __restrict__ flag)
{
    int nid = blockIdx.x * 4 + (threadIdx.x >> 6);
    if (nid >= O_NODES) return;
    int lane = threadIdx.x & 63;
    int isf = flag[1];

    int off = offsets[nid];
    int deg = count[nid];
    float mm = mbuf[nid];

    uint2 vt = *(const uint2*)(Pu + (long)nid * 256 + lane * 2);
    uint2 vb = *(const uint2*)(Pu + (long)nid * 256 + 128 + lane * 2);
    f32x4 ot0 = unpack4_fp8(vt.x), ot1 = unpack4_fp8(vt.y);
    f32x4 ob0 = unpack4_fp8(vb.x), ob1 = unpack4_fp8(vb.y);
    float b1v[8];
    #pragma unroll
    for (int j = 0; j < 8; ++j) b1v[j] = load_f(b1, lane * 8 + j, isf);

    float accS[8], accO[8];
    #pragma unroll
    for (int j = 0; j < 8; ++j) { accS[j] = 0.f; accO[j] = 0.f; }
    float wS = 0.f, wO = 0.f;

    for (int base = 0; base < deg; base += 64) {
        int nb = deg - base; if (nb > 64) nb = 64;
        // lane-parallel record load: ONE wave instruction covers 64 incidences
        int pr = 0; float w = 0.f;
        if (lane < nb) {
            int2 rec = inc2[off + base + lane];
            pr = rec.x;
            w  = __expf(__int_as_float(rec.y) - mm);
        }

        int i = 0;
        // steady state: unpredicated batch of 8 (8 x 512B loads in flight)
        while (i + 8 <= nb) {
            unsigned pv0[8], pv1[8]; float wk[8]; int rl[8];
            #pragma unroll
            for (int k = 0; k < 8; ++k) {
                int prk = __shfl(pr, i + k, 64);
                wk[k] = __shfl(w, i + k, 64);
                rl[k] = prk & 1;
                uint2 v = *(const uint2*)(Pu + (long)(prk >> 1) * 256 + (rl[k] ? 0 : 128) + lane * 2);
                pv0[k] = v.x; pv1[k] = v.y;
            }
            #pragma unroll
            for (int k = 0; k < 8; ++k) {
                f32x4 p0 = unpack4_fp8(pv0[k]), p1 = unpack4_fp8(pv1[k]);
                float wkk = wk[k];
                if (rl[k]) {     // wave-uniform branch
                    wO += wkk;
                    #pragma unroll
                    for (int j = 0; j < 4; ++j) accO[j]     += wkk * fmaxf(ob0[j] + p0[j] + b1v[j], 0.f);
                    #pragma unroll
                    for (int j = 0; j < 4; ++j) accO[4 + j] += wkk * fmaxf(ob1[j] + p1[j] + b1v[4 + j], 0.f);
                } else {
                    wS += wkk;
                    #pragma unroll
                    for (int j = 0; j < 4; ++j) accS[j]     += wkk * fmaxf(ot0[j] + p0[j] + b1v[j], 0.f);
                    #pragma unroll
                    for (int j = 0; j < 4; ++j) accS[4 + j] += wkk * fmaxf(ot1[j] + p1[j] + b1v[4 + j], 0.f);
                }
            }
            i += 8;
        }
        // remainder (predicated)
        while (i < nb) {
            int kb = nb - i; if (kb > 8) kb = 8;
            unsigned pv0[8], pv1[8]; float wk[8]; int rl[8];
            #pragma unroll
            for (int k = 0; k < 8; ++k) if (k < kb) {
                int prk = __shfl(pr, i + k, 64);
                wk[k] = __shfl(w, i + k, 64);
                rl[k] = prk & 1;
                uint2 v = *(const uint2*)(Pu + (long)(prk >> 1) * 256 + (rl[k] ? 0 : 128) + lane * 2);
                pv0[k] = v.x; pv1[k] = v.y;
            }
            #pragma unroll
            for (int k = 0; k < 8; ++k) if (k < kb) {
                f32x4 p0 = unpack4_fp8(pv0[k]), p1 = unpack4_fp8(pv1[k]);
                float wkk = wk[k];
                if (rl[k]) {
                    wO += wkk;
                    #pragma unroll
                    for (int j = 0; j < 4; ++j) accO[j]     += wkk * fmaxf(ob0[j] + p0[j] + b1v[j], 0.f);
                    #pragma unroll
                    for (int j = 0; j < 4; ++j) accO[4 + j] += wkk * fmaxf(ob1[j] + p1[j] + b1v[4 + j], 0.f);
                } else {
                    wS += wkk;
                    #pragma unroll
                    for (int j = 0; j < 4; ++j) accS[j]     += wkk * fmaxf(ot0[j] + p0[j] + b1v[j], 0.f);
                    #pragma unroll
                    for (int j = 0; j < 4; ++j) accS[4 + j] += wkk * fmaxf(ot1[j] + p1[j] + b1v[4 + j], 0.f);
                }
            }
            i += kb;
        }
    }

    uint2 hs, ho;
    hs.x = pack4_fp8(accS[0], accS[1], accS[2], accS[3]);
    hs.y = pack4_fp8(accS[4], accS[5], accS[6], accS[7]);
    ho.x = pack4_fp8(accO[0], accO[1], accO[2], accO[3]);
    ho.y = pack4_fp8(accO[4], accO[5], accO[6], accO[7]);
    ((uint2*)Hcat)[(long)nid * 128 + lane]      = hs;
    ((uint2*)Hcat)[(long)nid * 128 + 64 + lane] = ho;
    if (lane == 0) { ws_s[nid] = wS; ws_o[nid] = wO; }
}

// ---------- node-level GEMM2 + fused finalize ----------
__global__ __launch_bounds__(512, 4) void gemm2_node(
    const unsigned* __restrict__ Hcat,
    const unsigned char* __restrict__ w2p,
    const float* __restrict__ mbuf,
    const float* __restrict__ ws_s, const float* __restrict__ ws_o,
    const void* __restrict__ objf, const void* __restrict__ b2,
    void* __restrict__ out, const int* __restrict__ flag)
{
    extern __shared__ char smem[];
    unsigned char* sA = (unsigned char*)smem;     // 32KB frags
    float* sS    = (float*)(smem + 32768);        // [64] each
    float* sSelf = sS + 64;
    float* sInv  = sS + 128;
    float* sWs   = sS + 192;
    float* sWo   = sS + 256;

    const int tid  = threadIdx.x;
    const int wave = tid >> 6;
    const int lane = tid & 63;
    const int l15  = lane & 15;
    const int lq   = lane >> 4;
    const long bs  = (long)blockIdx.x * 64;
    const int isf  = flag[1];

    if (tid < 64) {
        long node = bs + tid; if (node >= O_NODES) node = O_NODES - 1;
        float mm = mbuf[node];
        float mn = fmaxf(mm, 10.0f);
        float S     = __expf(mm - mn);
        float selfw = __expf(10.0f - mn);
        float wss = ws_s[node], wso = ws_o[node];
        sS[tid] = S; sSelf[tid] = selfw; sWs[tid] = wss; sWo[tid] = wso;
        sInv[tid] = 1.0f / (S * (wss + wso) + selfw);
    }

    f32x4 acc[4][2];
    #pragma unroll
    for (int mt = 0; mt < 4; ++mt)
        #pragma unroll
        for (int nt = 0; nt < 2; ++nt)
            acc[mt][nt] = (f32x4){0.f, 0.f, 0.f, 0.f};

    const ulonglong2* bq = (const ulonglong2*)w2p;
    #pragma unroll
    for (int kh = 0; kh < 2; ++kh) {
        #pragma unroll
        for (int it = 0; it < 8; ++it) {
            int q   = it * 512 + tid;
            int m15 = q & 15;
            int mtp = (q >> 4) & 1;
            int h   = (q >> 5) & 1;
            int lqk = (q >> 6) & 3;
            int tk  = (q >> 8) & 15;
            int m   = (h * 2 + mtp) * 16 + m15;
            long node = bs + m; if (node >= O_NODES) node = O_NODES - 1;
            uint2 v = *(const uint2*)(Hcat + node * 256 + kh * 128 + tk * 8 + lqk * 2);
            *(uint2*)(sA + h * 16384 + (tk * 64 + lqk * 16 + m15) * 16 + mtp * 8) = v;
        }
        __syncthreads();
        #pragma unroll 2
        for (int tk = 0; tk < 16; ++tk) {
            int kt = kh * 16 + tk;
            ulonglong2 av01 = *(const ulonglong2*)(sA + tk * 1024 + lane * 16);
            ulonglong2 av23 = *(const ulonglong2*)(sA + 16384 + tk * 1024 + lane * 16);
            ulonglong2 b    = bq[(kt * 8 + wave) * 64 + lane];
            long a0 = (long)av01.x, a1 = (long)av01.y;
            long a2 = (long)av23.x, a3 = (long)av23.y;
            acc[0][0] = mfma_fp8(a0, (long)b.x, acc[0][0]);
            acc[1][0] = mfma_fp8(a1, (long)b.x, acc[1][0]);
            acc[2][0] = mfma_fp8(a2, (long)b.x, acc[2][0]);
            acc[3][0] = mfma_fp8(a3, (long)b.x, acc[3][0]);
            acc[0][1] = mfma_fp8(a0, (long)b.y, acc[0][1]);
            acc[1][1] = mfma_fp8(a1, (long)b.y, acc[1][1]);
            acc[2][1] = mfma_fp8(a2, (long)b.y, acc[2][1]);
            acc[3][1] = mfma_fp8(a3, (long)b.y, acc[3][1]);
        }
        __syncthreads();
    }

    // fused finalize epilogue
    #pragma unroll
    for (int nt = 0; nt < 2; ++nt) {
        int c = wave * 32 + nt * 16 + l15;
        float b2c = load_f(b2, c, isf);
        float b2d = load_f(b2, 256 + c, isf);
        #pragma unroll
        for (int mt = 0; mt < 4; ++mt) {
            #pragma unroll
            for (int r = 0; r < 4; ++r) {
                int row = mt * 16 + lq * 4 + r;
                long node = bs + row;
                if (node < O_NODES) {
                    float o = load_f(objf, node * 256 + c, isf);
                    float val = (sS[row] * (acc[mt][nt][r] + sWs[row] * b2c + sWo[row] * b2d)
                                 + sSelf[row] * o) * sInv[row];
                    if (isf) ((float*)out)[node * 256 + c] = val;
                    else     ((unsigned short*)out)[node * 256 + c] = f2bf(val);
                }
            }
        }
    }
}

extern "C" void kernel_launch(void* const* d_in, const int* in_sizes, int n_in,
                              void* d_out, int out_size, void* d_ws, size_t ws_size,
                              hipStream_t stream) {
    const void* objf  = d_in[0];
    const int*  pairs = (const int*)d_in[1];
    const void* conf  = d_in[2];
    const void* W1    = d_in[3];
    const void* b1    = d_in[4];
    const void* W2    = d_in[5];
    const void* b2    = d_in[6];

    char* ws = (char*)d_ws;
    // layout (bytes):
    //   0        count   200000
    //   200000   mbuf    200000
    //   400000   flag    64
    //   400064   offsets 200000
    //   600064   cursor  200000
    //   800064   inc2    3200000   (int2 records {partner<<1|role, conf})
    //   4000064  w1p     262144
    //   4262208  w2p     262144
    //   4524352  ws_s    200000
    //   4724352  ws_o    200000
    //   4924352  P       51200000   (fp8 [50k][1024])
    //   56124352 objf8   12800000   (dead after gemm1_node)
    //   56124352 Hcat    51200000   (overlays objf8; written by node_accum)
    //   total need = 107,324,352  (< 118.1 MB proven available)
    int*   count   = (int*)  ws;
    float* mbuf    = (float*)(ws + 200000);
    int*   flag    = (int*)  (ws + 400000);
    int*   offsets = (int*)  (ws + 400064);
    int*   cursor  = (int*)  (ws + 600064);
    int2*  inc2    = (int2*) (ws + 800064);
    unsigned char* w1p = (unsigned char*)(ws + 4000064);
    unsigned char* w2p = (unsigned char*)(ws + 4262208);
    float* wss     = (float*)(ws + 4524352);
    float* wso     = (float*)(ws + 4724352);
    unsigned char* P     = (unsigned char*)(ws + 4924352);
    unsigned*      objf8 = (unsigned*)(ws + 56124352);
    unsigned char* Hcat  = (unsigned char*)(ws + 56124352);

    hipMemsetAsync(count, 0, 400064, stream);   // count + mbuf(0) + flag

    mega_setup<<<MEGA_A + MEGA_B + MEGA_C + 1, 256, 0, stream>>>(
        objf, pairs, conf, W1, W2, objf8, w1p, w2p, mbuf, count, flag);

    scan50k<<<1, SCAN_T, 0, stream>>>(count, offsets, cursor);
    scatter_inc<<<(N_EDGES + 255) / 256, 256, 0, stream>>>(pairs, conf, cursor, inc2, flag);

    gemm1_node<<<2 * ((O_NODES + 63) / 64), 512, 33792, stream>>>(objf8, w1p, P);

    node_accum<<<(O_NODES + 3) / 4, 256, 0, stream>>>(
        (const unsigned*)P, inc2, offsets, count, mbuf, b1, Hcat, wss, wso, flag);

    gemm2_node<<<(O_NODES + 63) / 64, 512, 34048, stream>>>(
        (const unsigned*)Hcat, w2p, mbuf, wss, wso, objf, b2, d_out, flag);
}

// Round 3
// 377.087 us; speedup vs baseline: 1.2020x; 1.0275x over previous
//
#include <hip/hip_runtime.h>
#include <hip/hip_bf16.h>
#include <hip/hip_fp8.h>

#define O_NODES 50000
#define N_EDGES 200000
#define DD 256

typedef float f32x4 __attribute__((ext_vector_type(4)));

// ---------- fp8 e4m3 helpers ----------
__device__ __forceinline__ unsigned pack4_fp8(float a, float b, float c, float d) {
#if __has_builtin(__builtin_amdgcn_cvt_pk_fp8_f32)
    int v = __builtin_amdgcn_cvt_pk_fp8_f32(a, b, 0, false);
    v = __builtin_amdgcn_cvt_pk_fp8_f32(c, d, v, true);
    return (unsigned)v;
#else
    __hip_fp8_e4m3 x(a), y(b), z(c), w(d);
    return (unsigned)x.__x | ((unsigned)y.__x << 8) | ((unsigned)z.__x << 16) | ((unsigned)w.__x << 24);
#endif
}

__device__ __forceinline__ unsigned char f2fp8(float x) {
#if __has_builtin(__builtin_amdgcn_cvt_pk_fp8_f32)
    return (unsigned char)(__builtin_amdgcn_cvt_pk_fp8_f32(x, x, 0, false) & 0xff);
#else
    __hip_fp8_e4m3 t(x); return t.__x;
#endif
}

__device__ __forceinline__ f32x4 unpack4_fp8(unsigned v) {
#if __has_builtin(__builtin_amdgcn_cvt_pk_f32_fp8)
    auto lo = __builtin_amdgcn_cvt_pk_f32_fp8((int)v, false);
    auto hi = __builtin_amdgcn_cvt_pk_f32_fp8((int)v, true);
    return (f32x4){lo[0], lo[1], hi[0], hi[1]};
#else
    __hip_fp8_e4m3 t0, t1, t2, t3;
    t0.__x = v & 0xff; t1.__x = (v >> 8) & 0xff; t2.__x = (v >> 16) & 0xff; t3.__x = (v >> 24) & 0xff;
    return (f32x4){(float)t0, (float)t1, (float)t2, (float)t3};
#endif
}

__device__ __forceinline__ f32x4 mfma_fp8(long a, long b, f32x4 c) {
    return __builtin_amdgcn_mfma_f32_16x16x32_fp8_fp8(a, b, c, 0, 0, 0);
}

// ---------- generic input helpers ----------
__device__ __forceinline__ int get_pair(const int* __restrict__ p, long e, int which, int is32) {
    return is32 ? p[2 * e + which] : p[4 * e + 2 * which];
}

__device__ __forceinline__ float load_f(const void* p, long i, int is_f32) {
    if (is_f32) return ((const float*)p)[i];
    unsigned short u = ((const unsigned short*)p)[i];
    return __uint_as_float((unsigned)u << 16);
}

__device__ __forceinline__ float bf2f(unsigned short u) {
    return __uint_as_float((unsigned)u << 16);
}

__device__ __forceinline__ unsigned short f2bf(float x) {
    __hip_bfloat16 h = __float2bfloat16(x);
    return *(unsigned short*)&h;
}

// wave-collective dtype probes (call with full wave active, before any divergence)
__device__ __forceinline__ int detect_is32_w(const int* __restrict__ pairs) {
    int lane = threadIdx.x & 63;
    unsigned long long m = __ballot(pairs[2 * lane + 1] != 0);  // int64 high words all 0
    return m != 0ull;
}
__device__ __forceinline__ int detect_isf_w(const unsigned short* __restrict__ w) {
    int lane = threadIdx.x & 63;
    unsigned short u = w[2 * lane];
    float v = fabsf(__uint_as_float((unsigned)u << 16));
    unsigned long long m = __ballot(v > 0.004f && v < 16.0f);
    return (__popcll(m) < 32) ? 1 : 0;   // low halves mostly out-of-range => f32
}

// ---------- mega setup: cvt_objf | pack W1cat+W2cat | edge max+count | bconv | flag ----------
#define MEGA_A 12500
#define MEGA_B 2048
#define MEGA_C 782
__global__ __launch_bounds__(256) void mega_setup(
    const void* __restrict__ objf, const int* __restrict__ pairs, const void* __restrict__ conf,
    const void* __restrict__ W1, const void* __restrict__ W2,
    const void* __restrict__ b1, const void* __restrict__ b2,
    unsigned* __restrict__ objf8, unsigned char* __restrict__ w1p, unsigned char* __restrict__ w2p,
    float* __restrict__ b1f, float* __restrict__ b2f,
    float* __restrict__ mbuf, int* __restrict__ count, int* __restrict__ flag)
{
    int b = blockIdx.x, t = threadIdx.x;
    if (b < MEGA_A) {
        int isf = detect_isf_w((const unsigned short*)objf);
        int i4 = b * 256 + t;
        float x0, x1, x2, x3;
        if (isf) {
            float4 v = ((const float4*)objf)[i4];
            x0 = v.x; x1 = v.y; x2 = v.z; x3 = v.w;
        } else {
            ushort4 u = ((const ushort4*)objf)[i4];
            x0 = bf2f(u.x); x1 = bf2f(u.y); x2 = bf2f(u.z); x3 = bf2f(u.w);
        }
        objf8[i4] = pack4_fp8(x0, x1, x2, x3);
    } else if (b < MEGA_A + MEGA_B) {
        int isf = detect_isf_w((const unsigned short*)objf);
        int bb = b - MEGA_A;
        int idx = ((bb & 1023) << 8) + t;
        if (bb < 1024) {   // W1cat [256][1024]
            int j = idx & 7, half = (idx >> 3) & 1, lane = (idx >> 4) & 63;
            int p = (idx >> 10) & 31, tk = idx >> 15;
            int k = tk * 32 + (lane >> 4) * 8 + j;
            int n = (2 * p + half) * 16 + (lane & 15);
            long src = (n < 512) ? ((long)k * 512 + n) : ((long)(256 + k) * 512 + (n - 512));
            w1p[idx] = f2fp8(load_f(W1, src, isf));
        } else {           // W2cat [1024][256]
            int j = idx & 7, half = (idx >> 3) & 1, lane = (idx >> 4) & 63;
            int p = (idx >> 10) & 7, tk = idx >> 13;
            int k = tk * 32 + (lane >> 4) * 8 + j;
            int n = (2 * p + half) * 16 + (lane & 15);
            long src = (k < 512) ? ((long)k * 512 + n) : ((long)(k - 512) * 512 + 256 + n);
            w2p[idx] = f2fp8(load_f(W2, src, isf));
        }
    } else if (b < MEGA_A + MEGA_B + MEGA_C) {
        int is32 = detect_is32_w(pairs);
        int isf  = detect_isf_w((const unsigned short*)objf);
        int i = (b - MEGA_A - MEGA_B) * 256 + t;
        if (i >= N_EDGES) return;
        int s = get_pair(pairs, i, 0, is32);
        int o = get_pair(pairs, i, 1, is32);
        float c = load_f(conf, i, isf);
        int cb = __float_as_int(c);
        // mbuf memset 0; mbuf = max(0, max conf) — any shift point m works since we
        // rescale by S = exp(mbuf - max(mbuf,10)) in the epilogue (exact identity).
        atomicMax((int*)&mbuf[s], cb);
        atomicMax((int*)&mbuf[o], cb);
        atomicAdd(&count[s], 1);
        atomicAdd(&count[o], 1);
    } else if (b == MEGA_A + MEGA_B + MEGA_C) {
        int isf = detect_isf_w((const unsigned short*)objf);
        b1f[t]       = load_f(b1, t, isf);
        b1f[256 + t] = load_f(b1, 256 + t, isf);
        b2f[t]       = load_f(b2, t, isf);
        b2f[256 + t] = load_f(b2, 256 + t, isf);
    } else {
        int is32 = detect_is32_w(pairs);
        int isf  = detect_isf_w((const unsigned short*)objf);
        if (t == 0) { flag[0] = is32; flag[1] = isf; }
    }
}

// coalesced single-block scan, int4 per thread; emits cursor + packed meta {off,deg,mm}
#define SCAN_T 1024
__global__ __launch_bounds__(SCAN_T) void scan50k(const int* __restrict__ count,
                                                  const float* __restrict__ mbuf,
                                                  int* __restrict__ cursor,
                                                  int4* __restrict__ meta) {
    __shared__ int wsum[16];
    __shared__ int carry_s;
    int t = threadIdx.x;
    int lane = t & 63, wid = t >> 6;
    if (t == 0) carry_s = 0;
    __syncthreads();
    for (int base = 0; base < O_NODES; base += 4 * SCAN_T) {
        int i4 = base + t * 4;
        int4 c = make_int4(0, 0, 0, 0);
        if (i4 < O_NODES) c = *(const int4*)(count + i4);   // O_NODES % 4 == 0
        int s1 = c.x, s2 = s1 + c.y, s3 = s2 + c.z, s4 = s3 + c.w;
        int v = s4;
        #pragma unroll
        for (int d = 1; d < 64; d <<= 1) {
            int u = __shfl_up(v, d, 64);
            if (lane >= d) v += u;
        }
        if (lane == 63) wsum[wid] = v;
        __syncthreads();
        if (wid == 0) {
            int s = (lane < 16) ? wsum[lane] : 0;
            #pragma unroll
            for (int d = 1; d < 16; d <<= 1) {
                int u = __shfl_up(s, d, 64);
                if (lane >= d) s += u;
            }
            if (lane < 16) wsum[lane] = s;
        }
        __syncthreads();
        int wprefix = (wid == 0) ? 0 : wsum[wid - 1];
        int excl = carry_s + wprefix + v - s4;
        if (i4 < O_NODES) {
            float4 mb = *(const float4*)(mbuf + i4);
            *(int4*)(cursor + i4) = make_int4(excl, excl + s1, excl + s2, excl + s3);
            meta[i4 + 0] = make_int4(excl,      c.x, __float_as_int(mb.x), 0);
            meta[i4 + 1] = make_int4(excl + s1, c.y, __float_as_int(mb.y), 0);
            meta[i4 + 2] = make_int4(excl + s2, c.z, __float_as_int(mb.z), 0);
            meta[i4 + 3] = make_int4(excl + s3, c.w, __float_as_int(mb.w), 0);
        }
        int total = wsum[15];
        __syncthreads();
        if (t == 0) carry_s += total;
        __syncthreads();
    }
}

// scatter: write full incidence records {partner<<1|role, conf_bits}
__global__ void scatter_inc(const int* __restrict__ pairs, const void* __restrict__ conf,
                            int* __restrict__ cursor, int2* __restrict__ inc2,
                            const int* __restrict__ flag) {
    int i = blockIdx.x * 256 + threadIdx.x;
    if (i >= N_EDGES) return;
    int is32 = flag[0], isf = flag[1];
    int s = get_pair(pairs, i, 0, is32);
    int o = get_pair(pairs, i, 1, is32);
    int cb = __float_as_int(load_f(conf, i, isf));
    int ps = atomicAdd(&cursor[s], 1);
    inc2[ps] = make_int2((o << 1) | 0, cb);   // s is SUB of edge i, partner o
    int po = atomicAdd(&cursor[o], 1);
    inc2[po] = make_int2((s << 1) | 1, cb);   // o is OBJ of edge i, partner s
}

// ---------- node-level GEMM1: P[50k][1024] fp8 = objf8[50k][256] @ W1cat[256][1024] ----------
__global__ __launch_bounds__(512, 4) void gemm1_node(
    const unsigned* __restrict__ objf8,
    const unsigned char* __restrict__ w1p,
    unsigned char* __restrict__ P)
{
    extern __shared__ char smem[];
    unsigned char* sA = (unsigned char*)smem;    // frag: 16KB; epi: 64x528 = 33792

    const int tid  = threadIdx.x;
    const int wave = tid >> 6;
    const int lane = tid & 63;
    const int l15  = lane & 15;
    const int lq   = lane >> 4;
    const int mb   = blockIdx.x >> 1;
    const int nh   = blockIdx.x & 1;
    const long bs  = (long)mb * 64;

    // stage A: 64 rows x 32 k-octets = 2048 uint2; 4 per thread, frag-major dest
    #pragma unroll
    for (int it = 0; it < 4; ++it) {
        int q   = it * 512 + tid;
        int m15 = q & 15;
        int mtp = (q >> 4) & 1;
        int h   = (q >> 5) & 1;
        int lqk = (q >> 6) & 3;
        int tk  = (q >> 8) & 7;
        int m   = (h * 2 + mtp) * 16 + m15;
        long node = bs + m; if (node >= O_NODES) node = O_NODES - 1;
        uint2 v = *(const uint2*)(objf8 + node * 64 + tk * 8 + lqk * 2);
        *(uint2*)(sA + h * 8192 + (tk * 64 + lqk * 16 + m15) * 16 + mtp * 8) = v;
    }
    __syncthreads();

    f32x4 acc[4][4];
    #pragma unroll
    for (int mt = 0; mt < 4; ++mt)
        #pragma unroll
        for (int nt = 0; nt < 4; ++nt)
            acc[mt][nt] = (f32x4){0.f, 0.f, 0.f, 0.f};

    {
        const ulonglong2* bq = (const ulonglong2*)w1p;
        const int pbase = nh * 16 + wave * 2;
        #pragma unroll 2
        for (int tk = 0; tk < 8; ++tk) {
            ulonglong2 av01 = *(const ulonglong2*)(sA + tk * 1024 + lane * 16);
            ulonglong2 av23 = *(const ulonglong2*)(sA + 8192 + tk * 1024 + lane * 16);
            ulonglong2 b01  = bq[(tk * 32 + pbase) * 64 + lane];
            ulonglong2 b23  = bq[(tk * 32 + pbase + 1) * 64 + lane];
            long a0 = (long)av01.x, a1 = (long)av01.y;
            long a2 = (long)av23.x, a3 = (long)av23.y;
            acc[0][0] = mfma_fp8(a0, (long)b01.x, acc[0][0]);
            acc[1][0] = mfma_fp8(a1, (long)b01.x, acc[1][0]);
            acc[2][0] = mfma_fp8(a2, (long)b01.x, acc[2][0]);
            acc[3][0] = mfma_fp8(a3, (long)b01.x, acc[3][0]);
            acc[0][1] = mfma_fp8(a0, (long)b01.y, acc[0][1]);
            acc[1][1] = mfma_fp8(a1, (long)b01.y, acc[1][1]);
            acc[2][1] = mfma_fp8(a2, (long)b01.y, acc[2][1]);
            acc[3][1] = mfma_fp8(a3, (long)b01.y, acc[3][1]);
            acc[0][2] = mfma_fp8(a0, (long)b23.x, acc[0][2]);
            acc[1][2] = mfma_fp8(a1, (long)b23.x, acc[1][2]);
            acc[2][2] = mfma_fp8(a2, (long)b23.x, acc[2][2]);
            acc[3][2] = mfma_fp8(a3, (long)b23.x, acc[3][2]);
            acc[0][3] = mfma_fp8(a0, (long)b23.y, acc[0][3]);
            acc[1][3] = mfma_fp8(a1, (long)b23.y, acc[1][3]);
            acc[2][3] = mfma_fp8(a2, (long)b23.y, acc[2][3]);
            acc[3][3] = mfma_fp8(a3, (long)b23.y, acc[3][3]);
        }
    }
    __syncthreads();

    // fp8 row-major (stride 528) -> coalesced stream into P
    #pragma unroll
    for (int nt = 0; nt < 4; ++nt) {
        int c = wave * 64 + nt * 16 + l15;
        #pragma unroll
        for (int mt = 0; mt < 4; ++mt) {
            #pragma unroll
            for (int r = 0; r < 4; ++r) {
                sA[(mt * 16 + lq * 4 + r) * 528 + c] = f2fp8(acc[mt][nt][r]);
            }
        }
    }
    __syncthreads();
    #pragma unroll
    for (int it = 0; it < 4; ++it) {
        int idx = it * 512 + tid;
        int row = idx >> 5;
        int ch  = idx & 31;
        if (bs + row < O_NODES) {
            uint4 v = *(const uint4*)(sA + row * 528 + ch * 16);
            ((uint4*)P)[(bs + row) * 64 + nh * 32 + ch] = v;
        }
    }
}

// ---------- per-node weighted-h accumulation (TWO waves per node, 256 dims each) ----------
// h_e = relu(Ptop[sub_e] + Pbot[obj_e] + b1); Hcat[n] = [ Σ_{sub} w h | Σ_{obj} w h ] fp8
__global__ __launch_bounds__(256) void node_accum(
    const unsigned* __restrict__ Pu,     // P as uints, row = 256 uints
    const int2* __restrict__ inc2,
    const int4* __restrict__ meta,
    const float4* __restrict__ b1f4,
    unsigned* __restrict__ Hcat_u,       // row = 256 uints: [Hs 128 | Ho 128]
    float* __restrict__ ws_s, float* __restrict__ ws_o)
{
    int wv  = threadIdx.x >> 6;
    int nid = blockIdx.x * 2 + (wv >> 1);
    if (nid >= O_NODES) return;
    int hw   = wv & 1;                   // which 256-dim half this wave owns
    int lane = threadIdx.x & 63;

    int4 mt = meta[nid];
    int off = mt.x, deg = mt.y;
    float mm = __int_as_float(mt.z);

    long prow = (long)nid * 256;
    unsigned st = Pu[prow + hw * 64 + lane];
    unsigned sb = Pu[prow + 128 + hw * 64 + lane];
    f32x4 ot = unpack4_fp8(st), ob = unpack4_fp8(sb);
    float4 bq = b1f4[hw * 64 + lane];
    f32x4 b1v = {bq.x, bq.y, bq.z, bq.w};

    f32x4 accS = {0.f, 0.f, 0.f, 0.f}, accO = {0.f, 0.f, 0.f, 0.f};
    float wS = 0.f, wO = 0.f;

    for (int base = 0; base < deg; base += 64) {
        int nb = deg - base; if (nb > 64) nb = 64;
        int pr = 0; float w = 0.f;
        if (lane < nb) {
            int2 rec = inc2[off + base + lane];
            pr = rec.x;
            w  = __expf(__int_as_float(rec.y) - mm);
        }
        int i = 0;
        while (i + 8 <= nb) {   // steady state: 8 x 256B loads in flight
            unsigned pv[8]; float wk[8]; int rl[8];
            #pragma unroll
            for (int k = 0; k < 8; ++k) {
                int prk = __shfl(pr, i + k, 64);
                wk[k] = __shfl(w, i + k, 64);
                rl[k] = prk & 1;
                pv[k] = Pu[(long)(prk >> 1) * 256 + (rl[k] ? 0 : 128) + hw * 64 + lane];
            }
            #pragma unroll
            for (int k = 0; k < 8; ++k) {
                f32x4 p = unpack4_fp8(pv[k]);
                float wkk = wk[k];
                if (rl[k]) {   // wave-uniform branch: nid is OBJ
                    wO += wkk;
                    #pragma unroll
                    for (int j = 0; j < 4; ++j) accO[j] += wkk * fmaxf(ob[j] + p[j] + b1v[j], 0.f);
                } else {       // nid is SUB
                    wS += wkk;
                    #pragma unroll
                    for (int j = 0; j < 4; ++j) accS[j] += wkk * fmaxf(ot[j] + p[j] + b1v[j], 0.f);
                }
            }
            i += 8;
        }
        while (i < nb) {        // remainder (predicated)
            int kb = nb - i; if (kb > 8) kb = 8;
            unsigned pv[8]; float wk[8]; int rl[8];
            #pragma unroll
            for (int k = 0; k < 8; ++k) if (k < kb) {
                int prk = __shfl(pr, i + k, 64);
                wk[k] = __shfl(w, i + k, 64);
                rl[k] = prk & 1;
                pv[k] = Pu[(long)(prk >> 1) * 256 + (rl[k] ? 0 : 128) + hw * 64 + lane];
            }
            #pragma unroll
            for (int k = 0; k < 8; ++k) if (k < kb) {
                f32x4 p = unpack4_fp8(pv[k]);
                float wkk = wk[k];
                if (rl[k]) {
                    wO += wkk;
                    #pragma unroll
                    for (int j = 0; j < 4; ++j) accO[j] += wkk * fmaxf(ob[j] + p[j] + b1v[j], 0.f);
                } else {
                    wS += wkk;
                    #pragma unroll
                    for (int j = 0; j < 4; ++j) accS[j] += wkk * fmaxf(ot[j] + p[j] + b1v[j], 0.f);
                }
            }
            i += kb;
        }
    }

    Hcat_u[prow + hw * 64 + lane]       = pack4_fp8(accS[0], accS[1], accS[2], accS[3]);
    Hcat_u[prow + 128 + hw * 64 + lane] = pack4_fp8(accO[0], accO[1], accO[2], accO[3]);
    if (lane == 0 && hw == 0) { ws_s[nid] = wS; ws_o[nid] = wO; }
}

// ---------- node-level GEMM2 + fused finalize ----------
__global__ __launch_bounds__(512, 4) void gemm2_node(
    const unsigned* __restrict__ Hcat,
    const unsigned char* __restrict__ w2p,
    const float* __restrict__ mbuf,
    const float* __restrict__ ws_s, const float* __restrict__ ws_o,
    const void* __restrict__ objf, const float* __restrict__ b2f,
    void* __restrict__ out, const int* __restrict__ flag)
{
    extern __shared__ char smem[];
    unsigned char* sA = (unsigned char*)smem;     // 32KB frags
    float* sS    = (float*)(smem + 32768);        // [64] each
    float* sSelf = sS + 64;
    float* sInv  = sS + 128;
    float* sWs   = sS + 192;
    float* sWo   = sS + 256;

    const int tid  = threadIdx.x;
    const int wave = tid >> 6;
    const int lane = tid & 63;
    const int l15  = lane & 15;
    const int lq   = lane >> 4;
    const long bs  = (long)blockIdx.x * 64;
    const int isf  = flag[1];

    if (tid < 64) {
        long node = bs + tid; if (node >= O_NODES) node = O_NODES - 1;
        float mm = mbuf[node];
        float mn = fmaxf(mm, 10.0f);
        float S     = __expf(mm - mn);
        float selfw = __expf(10.0f - mn);
        float wss = ws_s[node], wso = ws_o[node];
        sS[tid] = S; sSelf[tid] = selfw; sWs[tid] = wss; sWo[tid] = wso;
        sInv[tid] = 1.0f / (S * (wss + wso) + selfw);
    }

    f32x4 acc[4][2];
    #pragma unroll
    for (int mt = 0; mt < 4; ++mt)
        #pragma unroll
        for (int nt = 0; nt < 2; ++nt)
            acc[mt][nt] = (f32x4){0.f, 0.f, 0.f, 0.f};

    const ulonglong2* bq = (const ulonglong2*)w2p;
    #pragma unroll
    for (int kh = 0; kh < 2; ++kh) {
        #pragma unroll
        for (int it = 0; it < 8; ++it) {
            int q   = it * 512 + tid;
            int m15 = q & 15;
            int mtp = (q >> 4) & 1;
            int h   = (q >> 5) & 1;
            int lqk = (q >> 6) & 3;
            int tk  = (q >> 8) & 15;
            int m   = (h * 2 + mtp) * 16 + m15;
            long node = bs + m; if (node >= O_NODES) node = O_NODES - 1;
            uint2 v = *(const uint2*)(Hcat + node * 256 + kh * 128 + tk * 8 + lqk * 2);
            *(uint2*)(sA + h * 16384 + (tk * 64 + lqk * 16 + m15) * 16 + mtp * 8) = v;
        }
        __syncthreads();
        #pragma unroll 2
        for (int tk = 0; tk < 16; ++tk) {
            int kt = kh * 16 + tk;
            ulonglong2 av01 = *(const ulonglong2*)(sA + tk * 1024 + lane * 16);
            ulonglong2 av23 = *(const ulonglong2*)(sA + 16384 + tk * 1024 + lane * 16);
            ulonglong2 b    = bq[(kt * 8 + wave) * 64 + lane];
            long a0 = (long)av01.x, a1 = (long)av01.y;
            long a2 = (long)av23.x, a3 = (long)av23.y;
            acc[0][0] = mfma_fp8(a0, (long)b.x, acc[0][0]);
            acc[1][0] = mfma_fp8(a1, (long)b.x, acc[1][0]);
            acc[2][0] = mfma_fp8(a2, (long)b.x, acc[2][0]);
            acc[3][0] = mfma_fp8(a3, (long)b.x, acc[3][0]);
            acc[0][1] = mfma_fp8(a0, (long)b.y, acc[0][1]);
            acc[1][1] = mfma_fp8(a1, (long)b.y, acc[1][1]);
            acc[2][1] = mfma_fp8(a2, (long)b.y, acc[2][1]);
            acc[3][1] = mfma_fp8(a3, (long)b.y, acc[3][1]);
        }
        __syncthreads();
    }

    // fused finalize epilogue
    #pragma unroll
    for (int nt = 0; nt < 2; ++nt) {
        int c = wave * 32 + nt * 16 + l15;
        float b2c = b2f[c];
        float b2d = b2f[256 + c];
        #pragma unroll
        for (int mt = 0; mt < 4; ++mt) {
            #pragma unroll
            for (int r = 0; r < 4; ++r) {
                int row = mt * 16 + lq * 4 + r;
                long node = bs + row;
                if (node < O_NODES) {
                    float o = load_f(objf, node * 256 + c, isf);
                    float val = (sS[row] * (acc[mt][nt][r] + sWs[row] * b2c + sWo[row] * b2d)
                                 + sSelf[row] * o) * sInv[row];
                    if (isf) ((float*)out)[node * 256 + c] = val;
                    else     ((unsigned short*)out)[node * 256 + c] = f2bf(val);
                }
            }
        }
    }
}

extern "C" void kernel_launch(void* const* d_in, const int* in_sizes, int n_in,
                              void* d_out, int out_size, void* d_ws, size_t ws_size,
                              hipStream_t stream) {
    const void* objf  = d_in[0];
    const int*  pairs = (const int*)d_in[1];
    const void* conf  = d_in[2];
    const void* W1    = d_in[3];
    const void* b1    = d_in[4];
    const void* W2    = d_in[5];
    const void* b2    = d_in[6];

    char* ws = (char*)d_ws;
    // layout (bytes):
    //   0        count   200000
    //   200000   mbuf    200000
    //   400000   flag    64
    //   400064   cursor  200000
    //   600064   inc2    3200000   (int2 records {partner<<1|role, conf})
    //   3800064  w1p     262144
    //   4062208  w2p     262144
    //   4324352  ws_s    200000
    //   4524352  ws_o    200000
    //   4724352  b1f     2048
    //   4726400  b2f     2048
    //   4728448  meta    800000    (int4 {off,deg,mm,0})
    //   5528448  P       51200000  (fp8 [50k][1024])
    //   56728448 objf8   12800000  (dead after gemm1_node)
    //   56728448 Hcat    51200000  (overlays objf8; written by node_accum)
    //   total ≈ 107.93 MB (< 118.1 MB proven available)
    int*   count   = (int*)  ws;
    float* mbuf    = (float*)(ws + 200000);
    int*   flag    = (int*)  (ws + 400000);
    int*   cursor  = (int*)  (ws + 400064);
    int2*  inc2    = (int2*) (ws + 600064);
    unsigned char* w1p = (unsigned char*)(ws + 3800064);
    unsigned char* w2p = (unsigned char*)(ws + 4062208);
    float* wss     = (float*)(ws + 4324352);
    float* wso     = (float*)(ws + 4524352);
    float* b1f     = (float*)(ws + 4724352);
    float* b2f     = (float*)(ws + 4726400);
    int4*  meta    = (int4*) (ws + 4728448);
    unsigned char* P     = (unsigned char*)(ws + 5528448);
    unsigned*      objf8 = (unsigned*)(ws + 56728448);
    unsigned char* Hcat  = (unsigned char*)(ws + 56728448);

    hipMemsetAsync(count, 0, 400064, stream);   // count + mbuf(0) + flag

    mega_setup<<<MEGA_A + MEGA_B + MEGA_C + 2, 256, 0, stream>>>(
        objf, pairs, conf, W1, W2, b1, b2, objf8, w1p, w2p, b1f, b2f, mbuf, count, flag);

    scan50k<<<1, SCAN_T, 0, stream>>>(count, mbuf, cursor, meta);
    scatter_inc<<<(N_EDGES + 255) / 256, 256, 0, stream>>>(pairs, conf, cursor, inc2, flag);

    gemm1_node<<<2 * ((O_NODES + 63) / 64), 512, 33792, stream>>>(objf8, w1p, P);

    node_accum<<<(O_NODES + 1) / 2, 256, 0, stream>>>(
        (const unsigned*)P, inc2, meta, (const float4*)b1f, (unsigned*)Hcat, wss, wso);

    gemm2_node<<<(O_NODES + 63) / 64, 512, 34048, stream>>>(
        (const unsigned*)Hcat, w2p, mbuf, wss, wso, objf, b2f, d_out, flag);
}

// Round 4
// 312.653 us; speedup vs baseline: 1.4498x; 1.2061x over previous
//
#include <hip/hip_runtime.h>
#include <hip/hip_bf16.h>
#include <hip/hip_fp8.h>

#define O_NODES 50000
#define N_EDGES 200000
#define DD 256
#define S_SLOTS 32
#define OVF_CAP 4096

typedef float f32x4 __attribute__((ext_vector_type(4)));

// ---------- fp8 e4m3 helpers ----------
__device__ __forceinline__ unsigned pack4_fp8(float a, float b, float c, float d) {
#if __has_builtin(__builtin_amdgcn_cvt_pk_fp8_f32)
    int v = __builtin_amdgcn_cvt_pk_fp8_f32(a, b, 0, false);
    v = __builtin_amdgcn_cvt_pk_fp8_f32(c, d, v, true);
    return (unsigned)v;
#else
    __hip_fp8_e4m3 x(a), y(b), z(c), w(d);
    return (unsigned)x.__x | ((unsigned)y.__x << 8) | ((unsigned)z.__x << 16) | ((unsigned)w.__x << 24);
#endif
}

__device__ __forceinline__ unsigned char f2fp8(float x) {
#if __has_builtin(__builtin_amdgcn_cvt_pk_fp8_f32)
    return (unsigned char)(__builtin_amdgcn_cvt_pk_fp8_f32(x, x, 0, false) & 0xff);
#else
    __hip_fp8_e4m3 t(x); return t.__x;
#endif
}

__device__ __forceinline__ f32x4 unpack4_fp8(unsigned v) {
#if __has_builtin(__builtin_amdgcn_cvt_pk_f32_fp8)
    auto lo = __builtin_amdgcn_cvt_pk_f32_fp8((int)v, false);
    auto hi = __builtin_amdgcn_cvt_pk_f32_fp8((int)v, true);
    return (f32x4){lo[0], lo[1], hi[0], hi[1]};
#else
    __hip_fp8_e4m3 t0, t1, t2, t3;
    t0.__x = v & 0xff; t1.__x = (v >> 8) & 0xff; t2.__x = (v >> 16) & 0xff; t3.__x = (v >> 24) & 0xff;
    return (f32x4){(float)t0, (float)t1, (float)t2, (float)t3};
#endif
}

__device__ __forceinline__ f32x4 mfma_fp8(long a, long b, f32x4 c) {
    return __builtin_amdgcn_mfma_f32_16x16x32_fp8_fp8(a, b, c, 0, 0, 0);
}

// ---------- generic input helpers ----------
__device__ __forceinline__ int get_pair(const int* __restrict__ p, long e, int which, int is32) {
    return is32 ? p[2 * e + which] : p[4 * e + 2 * which];
}

__device__ __forceinline__ float load_f(const void* p, long i, int is_f32) {
    if (is_f32) return ((const float*)p)[i];
    unsigned short u = ((const unsigned short*)p)[i];
    return __uint_as_float((unsigned)u << 16);
}

__device__ __forceinline__ float bf2f(unsigned short u) {
    return __uint_as_float((unsigned)u << 16);
}

__device__ __forceinline__ unsigned short f2bf(float x) {
    __hip_bfloat16 h = __float2bfloat16(x);
    return *(unsigned short*)&h;
}

// wave-collective dtype probes (call with full wave active, before any divergence)
__device__ __forceinline__ int detect_is32_w(const int* __restrict__ pairs) {
    int lane = threadIdx.x & 63;
    unsigned long long m = __ballot(pairs[2 * lane + 1] != 0);  // int64 high words all 0
    return m != 0ull;
}
__device__ __forceinline__ int detect_isf_w(const unsigned short* __restrict__ w) {
    int lane = threadIdx.x & 63;
    unsigned short u = w[2 * lane];
    float v = fabsf(__uint_as_float((unsigned)u << 16));
    unsigned long long m = __ballot(v > 0.004f && v < 16.0f);
    return (__popcll(m) < 32) ? 1 : 0;   // low halves mostly out-of-range => f32
}

// ---------- mega setup: cvt_objf | pack W1cat+W2cat | edge max+count+SLOT WRITE | bconv | flag ----------
#define MEGA_A 12500
#define MEGA_B 2048
#define MEGA_C 782
__global__ __launch_bounds__(256) void mega_setup(
    const void* __restrict__ objf, const int* __restrict__ pairs, const void* __restrict__ conf,
    const void* __restrict__ W1, const void* __restrict__ W2,
    const void* __restrict__ b1, const void* __restrict__ b2,
    unsigned* __restrict__ objf8, unsigned char* __restrict__ w1p, unsigned char* __restrict__ w2p,
    float* __restrict__ b1f, float* __restrict__ b2f,
    float* __restrict__ mbuf, int* __restrict__ count, int* __restrict__ flag,
    int2* __restrict__ inc2, int4* __restrict__ ovf)
{
    int b = blockIdx.x, t = threadIdx.x;
    if (b < MEGA_A) {
        int isf = detect_isf_w((const unsigned short*)objf);
        int i4 = b * 256 + t;
        float x0, x1, x2, x3;
        if (isf) {
            float4 v = ((const float4*)objf)[i4];
            x0 = v.x; x1 = v.y; x2 = v.z; x3 = v.w;
        } else {
            ushort4 u = ((const ushort4*)objf)[i4];
            x0 = bf2f(u.x); x1 = bf2f(u.y); x2 = bf2f(u.z); x3 = bf2f(u.w);
        }
        objf8[i4] = pack4_fp8(x0, x1, x2, x3);
    } else if (b < MEGA_A + MEGA_B) {
        int isf = detect_isf_w((const unsigned short*)objf);
        int bb = b - MEGA_A;
        int idx = ((bb & 1023) << 8) + t;
        if (bb < 1024) {   // W1cat [256][1024]
            int j = idx & 7, half = (idx >> 3) & 1, lane = (idx >> 4) & 63;
            int p = (idx >> 10) & 31, tk = idx >> 15;
            int k = tk * 32 + (lane >> 4) * 8 + j;
            int n = (2 * p + half) * 16 + (lane & 15);
            long src = (n < 512) ? ((long)k * 512 + n) : ((long)(256 + k) * 512 + (n - 512));
            w1p[idx] = f2fp8(load_f(W1, src, isf));
        } else {           // W2cat [1024][256]
            int j = idx & 7, half = (idx >> 3) & 1, lane = (idx >> 4) & 63;
            int p = (idx >> 10) & 7, tk = idx >> 13;
            int k = tk * 32 + (lane >> 4) * 8 + j;
            int n = (2 * p + half) * 16 + (lane & 15);
            long src = (k < 512) ? ((long)k * 512 + n) : ((long)(k - 512) * 512 + 256 + n);
            w2p[idx] = f2fp8(load_f(W2, src, isf));
        }
    } else if (b < MEGA_A + MEGA_B + MEGA_C) {
        int is32 = detect_is32_w(pairs);
        int isf  = detect_isf_w((const unsigned short*)objf);
        int i = (b - MEGA_A - MEGA_B) * 256 + t;
        if (i >= N_EDGES) return;
        int s = get_pair(pairs, i, 0, is32);
        int o = get_pair(pairs, i, 1, is32);
        float c = load_f(conf, i, isf);
        int cb = __float_as_int(c);
        // mbuf memset 0; mbuf = max(0, max conf) — shift point is arbitrary; we rescale
        // by S = exp(mbuf - max(mbuf,10)) in the epilogue (exact identity).
        atomicMax((int*)&mbuf[s], cb);
        atomicMax((int*)&mbuf[o], cb);
        // slot writes (replaces scan+scatter): fixed 32 slots/node + rare overflow
        int idx_s = atomicAdd(&count[s], 1);
        int rec_s = (o << 1) | 0;           // s is SUB of edge i
        if (idx_s < S_SLOTS) inc2[(long)s * S_SLOTS + idx_s] = make_int2(rec_s, cb);
        else { int oi = atomicAdd(&flag[2], 1); if (oi < OVF_CAP) ovf[oi] = make_int4(s, rec_s, cb, 0); }
        int idx_o = atomicAdd(&count[o], 1);
        int rec_o = (s << 1) | 1;           // o is OBJ of edge i
        if (idx_o < S_SLOTS) inc2[(long)o * S_SLOTS + idx_o] = make_int2(rec_o, cb);
        else { int oi = atomicAdd(&flag[2], 1); if (oi < OVF_CAP) ovf[oi] = make_int4(o, rec_o, cb, 0); }
    } else if (b == MEGA_A + MEGA_B + MEGA_C) {
        int isf = detect_isf_w((const unsigned short*)objf);
        b1f[t]       = load_f(b1, t, isf);
        b1f[256 + t] = load_f(b1, 256 + t, isf);
        b2f[t]       = load_f(b2, t, isf);
        b2f[256 + t] = load_f(b2, 256 + t, isf);
    } else {
        int is32 = detect_is32_w(pairs);
        int isf  = detect_isf_w((const unsigned short*)objf);
        if (t == 0) { flag[0] = is32; flag[1] = isf; }
    }
}

// ---------- node-level GEMM1: P[50k][1024] fp8 = objf8[50k][256] @ W1cat[256][1024] ----------
__global__ __launch_bounds__(512, 4) void gemm1_node(
    const unsigned* __restrict__ objf8,
    const unsigned char* __restrict__ w1p,
    unsigned char* __restrict__ P)
{
    extern __shared__ char smem[];
    unsigned char* sA = (unsigned char*)smem;    // frag: 16KB; epi: 64x528 = 33792

    const int tid  = threadIdx.x;
    const int wave = tid >> 6;
    const int lane = tid & 63;
    const int l15  = lane & 15;
    const int lq   = lane >> 4;
    const int mb   = blockIdx.x >> 1;
    const int nh   = blockIdx.x & 1;
    const long bs  = (long)mb * 64;

    // stage A: 64 rows x 32 k-octets = 2048 uint2; 4 per thread, frag-major dest
    #pragma unroll
    for (int it = 0; it < 4; ++it) {
        int q   = it * 512 + tid;
        int m15 = q & 15;
        int mtp = (q >> 4) & 1;
        int h   = (q >> 5) & 1;
        int lqk = (q >> 6) & 3;
        int tk  = (q >> 8) & 7;
        int m   = (h * 2 + mtp) * 16 + m15;
        long node = bs + m; if (node >= O_NODES) node = O_NODES - 1;
        uint2 v = *(const uint2*)(objf8 + node * 64 + tk * 8 + lqk * 2);
        *(uint2*)(sA + h * 8192 + (tk * 64 + lqk * 16 + m15) * 16 + mtp * 8) = v;
    }
    __syncthreads();

    f32x4 acc[4][4];
    #pragma unroll
    for (int mt = 0; mt < 4; ++mt)
        #pragma unroll
        for (int nt = 0; nt < 4; ++nt)
            acc[mt][nt] = (f32x4){0.f, 0.f, 0.f, 0.f};

    {
        const ulonglong2* bq = (const ulonglong2*)w1p;
        const int pbase = nh * 16 + wave * 2;
        #pragma unroll 2
        for (int tk = 0; tk < 8; ++tk) {
            ulonglong2 av01 = *(const ulonglong2*)(sA + tk * 1024 + lane * 16);
            ulonglong2 av23 = *(const ulonglong2*)(sA + 8192 + tk * 1024 + lane * 16);
            ulonglong2 b01  = bq[(tk * 32 + pbase) * 64 + lane];
            ulonglong2 b23  = bq[(tk * 32 + pbase + 1) * 64 + lane];
            long a0 = (long)av01.x, a1 = (long)av01.y;
            long a2 = (long)av23.x, a3 = (long)av23.y;
            acc[0][0] = mfma_fp8(a0, (long)b01.x, acc[0][0]);
            acc[1][0] = mfma_fp8(a1, (long)b01.x, acc[1][0]);
            acc[2][0] = mfma_fp8(a2, (long)b01.x, acc[2][0]);
            acc[3][0] = mfma_fp8(a3, (long)b01.x, acc[3][0]);
            acc[0][1] = mfma_fp8(a0, (long)b01.y, acc[0][1]);
            acc[1][1] = mfma_fp8(a1, (long)b01.y, acc[1][1]);
            acc[2][1] = mfma_fp8(a2, (long)b01.y, acc[2][1]);
            acc[3][1] = mfma_fp8(a3, (long)b01.y, acc[3][1]);
            acc[0][2] = mfma_fp8(a0, (long)b23.x, acc[0][2]);
            acc[1][2] = mfma_fp8(a1, (long)b23.x, acc[1][2]);
            acc[2][2] = mfma_fp8(a2, (long)b23.x, acc[2][2]);
            acc[3][2] = mfma_fp8(a3, (long)b23.x, acc[3][2]);
            acc[0][3] = mfma_fp8(a0, (long)b23.y, acc[0][3]);
            acc[1][3] = mfma_fp8(a1, (long)b23.y, acc[1][3]);
            acc[2][3] = mfma_fp8(a2, (long)b23.y, acc[2][3]);
            acc[3][3] = mfma_fp8(a3, (long)b23.y, acc[3][3]);
        }
    }
    __syncthreads();

    // fp8 row-major (stride 528) -> coalesced stream into P
    #pragma unroll
    for (int nt = 0; nt < 4; ++nt) {
        int c = wave * 64 + nt * 16 + l15;
        #pragma unroll
        for (int mt = 0; mt < 4; ++mt) {
            #pragma unroll
            for (int r = 0; r < 4; ++r) {
                sA[(mt * 16 + lq * 4 + r) * 528 + c] = f2fp8(acc[mt][nt][r]);
            }
        }
    }
    __syncthreads();
    #pragma unroll
    for (int it = 0; it < 4; ++it) {
        int idx = it * 512 + tid;
        int row = idx >> 5;
        int ch  = idx & 31;
        if (bs + row < O_NODES) {
            uint4 v = *(const uint4*)(sA + row * 528 + ch * 16);
            ((uint4*)P)[(bs + row) * 64 + nh * 32 + ch] = v;
        }
    }
}

// ---------- per-node weighted-h accumulation ----------
// 2 waves/node (256-dim halves), 8 nodes/wave, software-pipelined across node PAIRS.
// Slot layout: inc2[node*32 + idx] -> one 64-lane load covers a node PAIR's records.
__global__ __launch_bounds__(256) void node_accum(
    const unsigned* __restrict__ Pu,     // P as uints, row = 256 uints
    const int2* __restrict__ inc2,       // [50000][32]
    const int* __restrict__ count,
    const float* __restrict__ mbuf,
    const int* __restrict__ flag,        // flag[2] = overflow count
    const int4* __restrict__ ovf,
    const float4* __restrict__ b1f4,
    unsigned* __restrict__ Hcat_u,       // row = 256 uints: [Hs 128 | Ho 128]
    float* __restrict__ ws_s, float* __restrict__ ws_o)
{
    const int wv    = threadIdx.x >> 6;
    const int hw    = wv & 1;                    // 256-dim half owned by this wave
    const int lane  = threadIdx.x & 63;
    const int slice = blockIdx.x * 2 + (wv >> 1);
    const int nbase = slice * 8;                 // 3125 blocks * 2 slices * 8 = 50000 exact

    // wave-parallel meta: lanes 0..7 hold count/mbuf for the 8 nodes
    int cq = 0; float mq = 0.f;
    if (lane < 8) { cq = count[nbase + lane]; mq = mbuf[nbase + lane]; }

    float4 bq = b1f4[hw * 64 + lane];
    f32x4 b1v = {bq.x, bq.y, bq.z, bq.w};

    const long slotbase = (long)nbase * S_SLOTS;
    const long prow0    = (long)nbase * 256;

    // prefetch pair 0: records (1 load = 2 nodes) + self rows
    int2 rec = inc2[slotbase + lane];
    unsigned st0 = Pu[prow0 +       hw * 64 + lane];
    unsigned sb0 = Pu[prow0 + 128 + hw * 64 + lane];
    unsigned st1 = Pu[prow0 + 256 + hw * 64 + lane];
    unsigned sb1 = Pu[prow0 + 384 + hw * 64 + lane];

    #pragma unroll 1
    for (int p = 0; p < 4; ++p) {
        const int n0 = nbase + 2 * p;
        // issue next pair's loads early (static addresses, no dependencies)
        int2 rec_n = make_int2(0, 0);
        unsigned stA = 0, sbA = 0, stB = 0, sbB = 0;
        if (p < 3) {
            rec_n = inc2[slotbase + (p + 1) * 64 + lane];
            long prw = (long)(n0 + 2) * 256;
            stA = Pu[prw +       hw * 64 + lane];
            sbA = Pu[prw + 128 + hw * 64 + lane];
            stB = Pu[prw + 256 + hw * 64 + lane];
            sbB = Pu[prw + 384 + hw * 64 + lane];
        }
        // per-lane weight: lanes 0..31 belong to n0, 32..63 to n0+1
        float mml = __shfl(mq, 2 * p + (lane >> 5), 64);
        float wl  = __expf(__int_as_float(rec.y) - mml);
        int   prl = rec.x;

        #pragma unroll
        for (int half = 0; half < 2; ++half) {
            const int n = n0 + half;
            const int deg = __shfl(cq, 2 * p + half, 64);
            const float mm = __shfl(mq, 2 * p + half, 64);
            const unsigned stc = half ? st1 : st0;
            const unsigned sbc = half ? sb1 : sb0;
            f32x4 ot = unpack4_fp8(stc), ob = unpack4_fp8(sbc);
            f32x4 accS = {0.f, 0.f, 0.f, 0.f}, accO = {0.f, 0.f, 0.f, 0.f};
            float wS = 0.f, wO = 0.f;
            const int lb = half * 32;
            const int nb = deg < S_SLOTS ? deg : S_SLOTS;
            int i = 0;
            while (i < nb) {
                int kb = nb - i; if (kb > 8) kb = 8;
                unsigned pv[8]; float wk[8]; int rl[8];
                #pragma unroll
                for (int k = 0; k < 8; ++k) if (k < kb) {
                    int prk = __shfl(prl, lb + i + k, 64);
                    wk[k] = __shfl(wl, lb + i + k, 64);
                    rl[k] = prk & 1;
                    pv[k] = Pu[(long)(prk >> 1) * 256 + (rl[k] ? 0 : 128) + hw * 64 + lane];
                }
                #pragma unroll
                for (int k = 0; k < 8; ++k) if (k < kb) {
                    f32x4 pp = unpack4_fp8(pv[k]);
                    float wkk = wk[k];
                    if (rl[k]) {   // wave-uniform: n is OBJ of this edge
                        wO += wkk;
                        #pragma unroll
                        for (int j = 0; j < 4; ++j) accO[j] += wkk * fmaxf(ob[j] + pp[j] + b1v[j], 0.f);
                    } else {       // n is SUB
                        wS += wkk;
                        #pragma unroll
                        for (int j = 0; j < 4; ++j) accS[j] += wkk * fmaxf(ot[j] + pp[j] + b1v[j], 0.f);
                    }
                }
                i += kb;
            }
            if (deg > S_SLOTS) {   // rare overflow: walk the global overflow list
                int no = flag[2]; if (no > OVF_CAP) no = OVF_CAP;
                for (int tt = 0; tt < no; ++tt) {
                    int4 o = ovf[tt];
                    if (o.x == n) {
                        int role = o.y & 1, partner = o.y >> 1;
                        float wv = __expf(__int_as_float(o.z) - mm);
                        unsigned pvv = Pu[(long)partner * 256 + (role ? 0 : 128) + hw * 64 + lane];
                        f32x4 pp = unpack4_fp8(pvv);
                        if (role) {
                            wO += wv;
                            #pragma unroll
                            for (int j = 0; j < 4; ++j) accO[j] += wv * fmaxf(ob[j] + pp[j] + b1v[j], 0.f);
                        } else {
                            wS += wv;
                            #pragma unroll
                            for (int j = 0; j < 4; ++j) accS[j] += wv * fmaxf(ot[j] + pp[j] + b1v[j], 0.f);
                        }
                    }
                }
            }
            long prow = (long)n * 256;
            Hcat_u[prow +       hw * 64 + lane] = pack4_fp8(accS[0], accS[1], accS[2], accS[3]);
            Hcat_u[prow + 128 + hw * 64 + lane] = pack4_fp8(accO[0], accO[1], accO[2], accO[3]);
            if (hw == 0 && lane == 0) { ws_s[n] = wS; ws_o[n] = wO; }
        }
        if (p < 3) { rec = rec_n; st0 = stA; sb0 = sbA; st1 = stB; sb1 = sbB; }
    }
}

// ---------- node-level GEMM2 + fused finalize ----------
__global__ __launch_bounds__(512, 4) void gemm2_node(
    const unsigned* __restrict__ Hcat,
    const unsigned char* __restrict__ w2p,
    const float* __restrict__ mbuf,
    const float* __restrict__ ws_s, const float* __restrict__ ws_o,
    const void* __restrict__ objf, const float* __restrict__ b2f,
    void* __restrict__ out, const int* __restrict__ flag)
{
    extern __shared__ char smem[];
    unsigned char* sA = (unsigned char*)smem;     // 32KB frags
    float* sS    = (float*)(smem + 32768);        // [64] each
    float* sSelf = sS + 64;
    float* sInv  = sS + 128;
    float* sWs   = sS + 192;
    float* sWo   = sS + 256;

    const int tid  = threadIdx.x;
    const int wave = tid >> 6;
    const int lane = tid & 63;
    const int l15  = lane & 15;
    const int lq   = lane >> 4;
    const long bs  = (long)blockIdx.x * 64;
    const int isf  = flag[1];

    if (tid < 64) {
        long node = bs + tid; if (node >= O_NODES) node = O_NODES - 1;
        float mm = mbuf[node];
        float mn = fmaxf(mm, 10.0f);
        float S     = __expf(mm - mn);
        float selfw = __expf(10.0f - mn);
        float wss = ws_s[node], wso = ws_o[node];
        sS[tid] = S; sSelf[tid] = selfw; sWs[tid] = wss; sWo[tid] = wso;
        sInv[tid] = 1.0f / (S * (wss + wso) + selfw);
    }

    f32x4 acc[4][2];
    #pragma unroll
    for (int mt = 0; mt < 4; ++mt)
        #pragma unroll
        for (int nt = 0; nt < 2; ++nt)
            acc[mt][nt] = (f32x4){0.f, 0.f, 0.f, 0.f};

    const ulonglong2* bq = (const ulonglong2*)w2p;
    #pragma unroll
    for (int kh = 0; kh < 2; ++kh) {
        #pragma unroll
        for (int it = 0; it < 8; ++it) {
            int q   = it * 512 + tid;
            int m15 = q & 15;
            int mtp = (q >> 4) & 1;
            int h   = (q >> 5) & 1;
            int lqk = (q >> 6) & 3;
            int tk  = (q >> 8) & 15;
            int m   = (h * 2 + mtp) * 16 + m15;
            long node = bs + m; if (node >= O_NODES) node = O_NODES - 1;
            uint2 v = *(const uint2*)(Hcat + node * 256 + kh * 128 + tk * 8 + lqk * 2);
            *(uint2*)(sA + h * 16384 + (tk * 64 + lqk * 16 + m15) * 16 + mtp * 8) = v;
        }
        __syncthreads();
        #pragma unroll 2
        for (int tk = 0; tk < 16; ++tk) {
            int kt = kh * 16 + tk;
            ulonglong2 av01 = *(const ulonglong2*)(sA + tk * 1024 + lane * 16);
            ulonglong2 av23 = *(const ulonglong2*)(sA + 16384 + tk * 1024 + lane * 16);
            ulonglong2 b    = bq[(kt * 8 + wave) * 64 + lane];
            long a0 = (long)av01.x, a1 = (long)av01.y;
            long a2 = (long)av23.x, a3 = (long)av23.y;
            acc[0][0] = mfma_fp8(a0, (long)b.x, acc[0][0]);
            acc[1][0] = mfma_fp8(a1, (long)b.x, acc[1][0]);
            acc[2][0] = mfma_fp8(a2, (long)b.x, acc[2][0]);
            acc[3][0] = mfma_fp8(a3, (long)b.x, acc[3][0]);
            acc[0][1] = mfma_fp8(a0, (long)b.y, acc[0][1]);
            acc[1][1] = mfma_fp8(a1, (long)b.y, acc[1][1]);
            acc[2][1] = mfma_fp8(a2, (long)b.y, acc[2][1]);
            acc[3][1] = mfma_fp8(a3, (long)b.y, acc[3][1]);
        }
        __syncthreads();
    }

    // fused finalize epilogue
    #pragma unroll
    for (int nt = 0; nt < 2; ++nt) {
        int c = wave * 32 + nt * 16 + l15;
        float b2c = b2f[c];
        float b2d = b2f[256 + c];
        #pragma unroll
        for (int mt = 0; mt < 4; ++mt) {
            #pragma unroll
            for (int r = 0; r < 4; ++r) {
                int row = mt * 16 + lq * 4 + r;
                long node = bs + row;
                if (node < O_NODES) {
                    float o = load_f(objf, node * 256 + c, isf);
                    float val = (sS[row] * (acc[mt][nt][r] + sWs[row] * b2c + sWo[row] * b2d)
                                 + sSelf[row] * o) * sInv[row];
                    if (isf) ((float*)out)[node * 256 + c] = val;
                    else     ((unsigned short*)out)[node * 256 + c] = f2bf(val);
                }
            }
        }
    }
}

extern "C" void kernel_launch(void* const* d_in, const int* in_sizes, int n_in,
                              void* d_out, int out_size, void* d_ws, size_t ws_size,
                              hipStream_t stream) {
    const void* objf  = d_in[0];
    const int*  pairs = (const int*)d_in[1];
    const void* conf  = d_in[2];
    const void* W1    = d_in[3];
    const void* b1    = d_in[4];
    const void* W2    = d_in[5];
    const void* b2    = d_in[6];

    char* ws = (char*)d_ws;
    // layout (bytes):
    //   0         count   200000
    //   200000    mbuf    200000
    //   400000    flag    64       (flag[2] = overflow counter)
    //   400064    ovf     65536    (int4 x 4096)
    //   465600    w1p     262144
    //   727744    w2p     262144
    //   989888    ws_s    200000
    //   1189888   ws_o    200000
    //   1389888   b1f     2048
    //   1391936   b2f     2048
    //   1393984   inc2    12800000 (int2 slots [50000][32])
    //   14193984  P       51200000 (fp8 [50k][1024])
    //   65393984  objf8   12800000 (dead after gemm1_node)
    //   65393984  Hcat    51200000 (overlays objf8; written by node_accum)
    //   end = 116,593,984  (< 118,124,352 proven available)
    int*   count   = (int*)  ws;
    float* mbuf    = (float*)(ws + 200000);
    int*   flag    = (int*)  (ws + 400000);
    int4*  ovf     = (int4*) (ws + 400064);
    unsigned char* w1p = (unsigned char*)(ws + 465600);
    unsigned char* w2p = (unsigned char*)(ws + 727744);
    float* wss     = (float*)(ws + 989888);
    float* wso     = (float*)(ws + 1189888);
    float* b1f     = (float*)(ws + 1389888);
    float* b2f     = (float*)(ws + 1391936);
    int2*  inc2    = (int2*) (ws + 1393984);
    unsigned char* P     = (unsigned char*)(ws + 14193984);
    unsigned*      objf8 = (unsigned*)(ws + 65393984);
    unsigned char* Hcat  = (unsigned char*)(ws + 65393984);

    hipMemsetAsync(count, 0, 400064, stream);   // count + mbuf(0) + flag(incl. ovf counter)

    mega_setup<<<MEGA_A + MEGA_B + MEGA_C + 2, 256, 0, stream>>>(
        objf, pairs, conf, W1, W2, b1, b2, objf8, w1p, w2p, b1f, b2f,
        mbuf, count, flag, inc2, ovf);

    gemm1_node<<<2 * ((O_NODES + 63) / 64), 512, 33792, stream>>>(objf8, w1p, P);

    node_accum<<<O_NODES / 16, 256, 0, stream>>>(
        (const unsigned*)P, inc2, count, mbuf, flag, ovf, (const float4*)b1f,
        (unsigned*)Hcat, wss, wso);

    gemm2_node<<<(O_NODES + 63) / 64, 512, 34048, stream>>>(
        (const unsigned*)Hcat, w2p, mbuf, wss, wso, objf, b2f, d_out, flag);
}

// Round 5
// 308.688 us; speedup vs baseline: 1.4684x; 1.0128x over previous
//
#include <hip/hip_runtime.h>
#include <hip/hip_bf16.h>
#include <hip/hip_fp8.h>

#define O_NODES 50000
#define N_EDGES 200000
#define DD 256
#define S_SLOTS 32
#define OVF_CAP 4096

typedef float f32x4 __attribute__((ext_vector_type(4)));

// ---------- fp8 e4m3 helpers ----------
__device__ __forceinline__ unsigned pack4_fp8(float a, float b, float c, float d) {
#if __has_builtin(__builtin_amdgcn_cvt_pk_fp8_f32)
    int v = __builtin_amdgcn_cvt_pk_fp8_f32(a, b, 0, false);
    v = __builtin_amdgcn_cvt_pk_fp8_f32(c, d, v, true);
    return (unsigned)v;
#else
    __hip_fp8_e4m3 x(a), y(b), z(c), w(d);
    return (unsigned)x.__x | ((unsigned)y.__x << 8) | ((unsigned)z.__x << 16) | ((unsigned)w.__x << 24);
#endif
}

__device__ __forceinline__ unsigned char f2fp8(float x) {
#if __has_builtin(__builtin_amdgcn_cvt_pk_fp8_f32)
    return (unsigned char)(__builtin_amdgcn_cvt_pk_fp8_f32(x, x, 0, false) & 0xff);
#else
    __hip_fp8_e4m3 t(x); return t.__x;
#endif
}

__device__ __forceinline__ f32x4 unpack4_fp8(unsigned v) {
#if __has_builtin(__builtin_amdgcn_cvt_pk_f32_fp8)
    auto lo = __builtin_amdgcn_cvt_pk_f32_fp8((int)v, false);
    auto hi = __builtin_amdgcn_cvt_pk_f32_fp8((int)v, true);
    return (f32x4){lo[0], lo[1], hi[0], hi[1]};
#else
    __hip_fp8_e4m3 t0, t1, t2, t3;
    t0.__x = v & 0xff; t1.__x = (v >> 8) & 0xff; t2.__x = (v >> 16) & 0xff; t3.__x = (v >> 24) & 0xff;
    return (f32x4){(float)t0, (float)t1, (float)t2, (float)t3};
#endif
}

__device__ __forceinline__ f32x4 mfma_fp8(long a, long b, f32x4 c) {
    return __builtin_amdgcn_mfma_f32_16x16x32_fp8_fp8(a, b, c, 0, 0, 0);
}

// ---------- generic input helpers ----------
__device__ __forceinline__ int get_pair(const int* __restrict__ p, long e, int which, int is32) {
    return is32 ? p[2 * e + which] : p[4 * e + 2 * which];
}

__device__ __forceinline__ float load_f(const void* p, long i, int is_f32) {
    if (is_f32) return ((const float*)p)[i];
    unsigned short u = ((const unsigned short*)p)[i];
    return __uint_as_float((unsigned)u << 16);
}

__device__ __forceinline__ float bf2f(unsigned short u) {
    return __uint_as_float((unsigned)u << 16);
}

__device__ __forceinline__ unsigned short f2bf(float x) {
    __hip_bfloat16 h = __float2bfloat16(x);
    return *(unsigned short*)&h;
}

// wave-collective dtype probes (call with full wave active, before any divergence)
__device__ __forceinline__ int detect_is32_w(const int* __restrict__ pairs) {
    int lane = threadIdx.x & 63;
    unsigned long long m = __ballot(pairs[2 * lane + 1] != 0);  // int64 high words all 0
    return m != 0ull;
}
__device__ __forceinline__ int detect_isf_w(const unsigned short* __restrict__ w) {
    int lane = threadIdx.x & 63;
    unsigned short u = w[2 * lane];
    float v = fabsf(__uint_as_float((unsigned)u << 16));
    unsigned long long m = __ballot(v > 0.004f && v < 16.0f);
    return (__popcll(m) < 32) ? 1 : 0;   // low halves mostly out-of-range => f32
}

// ---------- mega setup: pack W1cat+W2cat | edge max+count+slot write | bconv | flag ----------
// (objf->fp8 conversion folded into gemm1_node staging; no objf8 buffer anymore)
#define MEGA_B 2048
#define MEGA_C 782
__global__ __launch_bounds__(256) void mega_setup(
    const void* __restrict__ objf, const int* __restrict__ pairs, const void* __restrict__ conf,
    const void* __restrict__ W1, const void* __restrict__ W2,
    const void* __restrict__ b1, const void* __restrict__ b2,
    unsigned char* __restrict__ w1p, unsigned char* __restrict__ w2p,
    float* __restrict__ b1f, float* __restrict__ b2f,
    float* __restrict__ mbuf, int* __restrict__ count, int* __restrict__ flag,
    int2* __restrict__ inc2, int4* __restrict__ ovf)
{
    int b = blockIdx.x, t = threadIdx.x;
    if (b < MEGA_B) {
        int isf = detect_isf_w((const unsigned short*)objf);
        int idx = ((b & 1023) << 8) + t;
        if (b < 1024) {    // W1cat [256][1024], N-concat
            int j = idx & 7, half = (idx >> 3) & 1, lane = (idx >> 4) & 63;
            int p = (idx >> 10) & 31, tk = idx >> 15;
            int k = tk * 32 + (lane >> 4) * 8 + j;
            int n = (2 * p + half) * 16 + (lane & 15);
            long src = (n < 512) ? ((long)k * 512 + n) : ((long)(256 + k) * 512 + (n - 512));
            w1p[idx] = f2fp8(load_f(W1, src, isf));
        } else {           // W2cat [1024][256], K-concat
            int j = idx & 7, half = (idx >> 3) & 1, lane = (idx >> 4) & 63;
            int p = (idx >> 10) & 7, tk = idx >> 13;
            int k = tk * 32 + (lane >> 4) * 8 + j;
            int n = (2 * p + half) * 16 + (lane & 15);
            long src = (k < 512) ? ((long)k * 512 + n) : ((long)(k - 512) * 512 + 256 + n);
            w2p[idx] = f2fp8(load_f(W2, src, isf));
        }
    } else if (b < MEGA_B + MEGA_C) {
        int is32 = detect_is32_w(pairs);
        int isf  = detect_isf_w((const unsigned short*)objf);
        int i = (b - MEGA_B) * 256 + t;
        if (i >= N_EDGES) return;
        int s = get_pair(pairs, i, 0, is32);
        int o = get_pair(pairs, i, 1, is32);
        float c = load_f(conf, i, isf);
        c = fminf(fmaxf(c, -80.f), 80.f);        // keep exp finite; identity for |c|<=80
        int cb = __float_as_int(c);
        int eb = __float_as_int(__expf(c));      // records carry exp(conf); w = expc*exp(-mm)
        // mbuf memset 0; mbuf = max(0, max conf) — shift point arbitrary, rescaled exactly
        // by S = exp(mbuf - max(mbuf,10)) in the gemm2 epilogue.
        atomicMax((int*)&mbuf[s], cb);
        atomicMax((int*)&mbuf[o], cb);
        int idx_s = atomicAdd(&count[s], 1);
        int rec_s = (o << 1) | 0;                // s is SUB of edge i
        if (idx_s < S_SLOTS) inc2[(long)s * S_SLOTS + idx_s] = make_int2(rec_s, eb);
        else { int oi = atomicAdd(&flag[2], 1); if (oi < OVF_CAP) ovf[oi] = make_int4(s, rec_s, eb, 0); }
        int idx_o = atomicAdd(&count[o], 1);
        int rec_o = (s << 1) | 1;                // o is OBJ of edge i
        if (idx_o < S_SLOTS) inc2[(long)o * S_SLOTS + idx_o] = make_int2(rec_o, eb);
        else { int oi = atomicAdd(&flag[2], 1); if (oi < OVF_CAP) ovf[oi] = make_int4(o, rec_o, eb, 0); }
    } else if (b == MEGA_B + MEGA_C) {
        int isf = detect_isf_w((const unsigned short*)objf);
        b1f[t]       = load_f(b1, t, isf);
        b1f[256 + t] = load_f(b1, 256 + t, isf);
        b2f[t]       = load_f(b2, t, isf);
        b2f[256 + t] = load_f(b2, 256 + t, isf);
    } else {
        int is32 = detect_is32_w(pairs);
        int isf  = detect_isf_w((const unsigned short*)objf);
        if (t == 0) { flag[0] = is32; flag[1] = isf; }
    }
}

// ---------- node-level GEMM1: P[50k][1024] fp8 = cvt_fp8(objf) @ W1cat[256][1024] ----------
// objf rows are read directly (f32 or bf16) and converted to fp8 during LDS staging.
__global__ __launch_bounds__(512, 4) void gemm1_node(
    const void* __restrict__ objf,
    const unsigned char* __restrict__ w1p,
    unsigned char* __restrict__ P)
{
    extern __shared__ char smem[];
    unsigned char* sA = (unsigned char*)smem;    // frag: 16KB; epi: 64x528 = 33792

    const int isf = detect_isf_w((const unsigned short*)objf);

    const int tid  = threadIdx.x;
    const int wave = tid >> 6;
    const int lane = tid & 63;
    const int l15  = lane & 15;
    const int lq   = lane >> 4;
    const int mb   = blockIdx.x >> 1;
    const int nh   = blockIdx.x & 1;
    const long bs  = (long)mb * 64;

    // stage A: 64 rows x 32 k-octets = 2048 uint2; 4 per thread, cvt->fp8, frag-major dest
    #pragma unroll
    for (int it = 0; it < 4; ++it) {
        int q   = it * 512 + tid;
        int m15 = q & 15;
        int mtp = (q >> 4) & 1;
        int h   = (q >> 5) & 1;
        int lqk = (q >> 6) & 3;
        int tk  = (q >> 8) & 7;
        int m   = (h * 2 + mtp) * 16 + m15;
        long node = bs + m; if (node >= O_NODES) node = O_NODES - 1;
        long f4 = node * 64 + tk * 8 + lqk * 2;   // float4/ushort4 index (4 values each)
        uint2 v;
        if (isf) {
            float4 a = ((const float4*)objf)[f4];
            float4 c = ((const float4*)objf)[f4 + 1];
            v.x = pack4_fp8(a.x, a.y, a.z, a.w);
            v.y = pack4_fp8(c.x, c.y, c.z, c.w);
        } else {
            ushort4 a = ((const ushort4*)objf)[f4];
            ushort4 c = ((const ushort4*)objf)[f4 + 1];
            v.x = pack4_fp8(bf2f(a.x), bf2f(a.y), bf2f(a.z), bf2f(a.w));
            v.y = pack4_fp8(bf2f(c.x), bf2f(c.y), bf2f(c.z), bf2f(c.w));
        }
        *(uint2*)(sA + h * 8192 + (tk * 64 + lqk * 16 + m15) * 16 + mtp * 8) = v;
    }
    __syncthreads();

    f32x4 acc[4][4];
    #pragma unroll
    for (int mt = 0; mt < 4; ++mt)
        #pragma unroll
        for (int nt = 0; nt < 4; ++nt)
            acc[mt][nt] = (f32x4){0.f, 0.f, 0.f, 0.f};

    {
        const ulonglong2* bq = (const ulonglong2*)w1p;
        const int pbase = nh * 16 + wave * 2;
        #pragma unroll 2
        for (int tk = 0; tk < 8; ++tk) {
            ulonglong2 av01 = *(const ulonglong2*)(sA + tk * 1024 + lane * 16);
            ulonglong2 av23 = *(const ulonglong2*)(sA + 8192 + tk * 1024 + lane * 16);
            ulonglong2 b01  = bq[(tk * 32 + pbase) * 64 + lane];
            ulonglong2 b23  = bq[(tk * 32 + pbase + 1) * 64 + lane];
            long a0 = (long)av01.x, a1 = (long)av01.y;
            long a2 = (long)av23.x, a3 = (long)av23.y;
            acc[0][0] = mfma_fp8(a0, (long)b01.x, acc[0][0]);
            acc[1][0] = mfma_fp8(a1, (long)b01.x, acc[1][0]);
            acc[2][0] = mfma_fp8(a2, (long)b01.x, acc[2][0]);
            acc[3][0] = mfma_fp8(a3, (long)b01.x, acc[3][0]);
            acc[0][1] = mfma_fp8(a0, (long)b01.y, acc[0][1]);
            acc[1][1] = mfma_fp8(a1, (long)b01.y, acc[1][1]);
            acc[2][1] = mfma_fp8(a2, (long)b01.y, acc[2][1]);
            acc[3][1] = mfma_fp8(a3, (long)b01.y, acc[3][1]);
            acc[0][2] = mfma_fp8(a0, (long)b23.x, acc[0][2]);
            acc[1][2] = mfma_fp8(a1, (long)b23.x, acc[1][2]);
            acc[2][2] = mfma_fp8(a2, (long)b23.x, acc[2][2]);
            acc[3][2] = mfma_fp8(a3, (long)b23.x, acc[3][2]);
            acc[0][3] = mfma_fp8(a0, (long)b23.y, acc[0][3]);
            acc[1][3] = mfma_fp8(a1, (long)b23.y, acc[1][3]);
            acc[2][3] = mfma_fp8(a2, (long)b23.y, acc[2][3]);
            acc[3][3] = mfma_fp8(a3, (long)b23.y, acc[3][3]);
        }
    }
    __syncthreads();

    // fp8 row-major (stride 528) -> coalesced stream into P
    #pragma unroll
    for (int nt = 0; nt < 4; ++nt) {
        int c = wave * 64 + nt * 16 + l15;
        #pragma unroll
        for (int mt = 0; mt < 4; ++mt) {
            #pragma unroll
            for (int r = 0; r < 4; ++r) {
                sA[(mt * 16 + lq * 4 + r) * 528 + c] = f2fp8(acc[mt][nt][r]);
            }
        }
    }
    __syncthreads();
    #pragma unroll
    for (int it = 0; it < 4; ++it) {
        int idx = it * 512 + tid;
        int row = idx >> 5;
        int ch  = idx & 31;
        if (bs + row < O_NODES) {
            uint4 v = *(const uint4*)(sA + row * 528 + ch * 16);
            ((uint4*)P)[(bs + row) * 64 + nh * 32 + ch] = v;
        }
    }
}

// ---------- per-node weighted-h accumulation ----------
// 2 waves/node-slice (256-dim halves), 8 nodes serial per wave.
// Records read via wave-uniform SCALAR loads (static slot addresses) — no shfl/DS ops.
__global__ __launch_bounds__(256) void node_accum(
    const unsigned* __restrict__ Pu,     // P as uints, row = 256 uints
    const int2* __restrict__ inc2,       // [50000][32] {partner<<1|role, exp(conf) bits}
    const int* __restrict__ count,
    const float* __restrict__ mbuf,
    const int* __restrict__ flag,        // flag[2] = overflow count
    const int4* __restrict__ ovf,
    const float4* __restrict__ b1f4,
    unsigned* __restrict__ Hcat_u,       // row = 256 uints: [Hs 128 | Ho 128]
    float* __restrict__ ws_s, float* __restrict__ ws_o)
{
    const int lane = threadIdx.x & 63;
    const int hw   = (threadIdx.x >> 6) & 1;             // 256-dim half owned by this wave
    const int nbase = __builtin_amdgcn_readfirstlane(
        (blockIdx.x * 2 + (threadIdx.x >> 7)) * 8);      // 3125 blocks * 2 slices * 8 = 50000

    float4 bqv = b1f4[hw * 64 + lane];
    f32x4 b1v = {bqv.x, bqv.y, bqv.z, bqv.w};
    const int col = hw * 64 + lane;

    // prefetch node 0 self rows
    unsigned st = Pu[(long)nbase * 256 + col];
    unsigned sb = Pu[(long)nbase * 256 + 128 + col];

    #pragma unroll 1
    for (int t = 0; t < 8; ++t) {
        const int n = nbase + t;
        const int deg = count[n];                         // scalar load
        const float mm = mbuf[n];                         // scalar load
        const float emm = __expf(-mm);
        const int2* srec = inc2 + (long)n * S_SLOTS;
        // batch-0 records: scalar dwordx4 loads (slots always allocated; unused => ignored)
        int4 r0 = *(const int4*)(srec);
        int4 r1 = *(const int4*)(srec + 2);
        int4 r2 = *(const int4*)(srec + 4);
        int4 r3 = *(const int4*)(srec + 6);
        // prefetch next node's self rows
        unsigned stn = 0, sbn = 0;
        if (t < 7) {
            stn = Pu[(long)(n + 1) * 256 + col];
            sbn = Pu[(long)(n + 1) * 256 + 128 + col];
        }
        f32x4 ots = unpack4_fp8(st), obs = unpack4_fp8(sb);
        f32x4 otb, obb;
        #pragma unroll
        for (int j = 0; j < 4; ++j) { otb[j] = ots[j] + b1v[j]; obb[j] = obs[j] + b1v[j]; }

        f32x4 accS = {0.f, 0.f, 0.f, 0.f}, accO = {0.f, 0.f, 0.f, 0.f};
        float wS = 0.f, wO = 0.f;

        auto ACC = [&](int rx, int ry, unsigned pv) {
            float wk = __int_as_float(ry) * emm;
            f32x4 pp = unpack4_fp8(pv);
            if (rx & 1) {        // wave-uniform: n is OBJ of this edge
                wO += wk;
                #pragma unroll
                for (int j = 0; j < 4; ++j) accO[j] += wk * fmaxf(obb[j] + pp[j], 0.f);
            } else {             // n is SUB
                wS += wk;
                #pragma unroll
                for (int j = 0; j < 4; ++j) accS[j] += wk * fmaxf(otb[j] + pp[j], 0.f);
            }
        };

        const int nb = deg < S_SLOTS ? deg : S_SLOTS;
        for (int i = 0; i < nb; i += 8) {
            int kb = nb - i; if (kb > 8) kb = 8;
            if (i) {
                r0 = *(const int4*)(srec + i);
                r1 = *(const int4*)(srec + i + 2);
                r2 = *(const int4*)(srec + i + 4);
                r3 = *(const int4*)(srec + i + 6);
            }
            if (kb == 8) {       // fast path: 8 partner loads in flight, no predication
                unsigned p0 = Pu[(long)(r0.x >> 1) * 256 + ((r0.x & 1) ? 0 : 128) + col];
                unsigned p1 = Pu[(long)(r0.z >> 1) * 256 + ((r0.z & 1) ? 0 : 128) + col];
                unsigned p2 = Pu[(long)(r1.x >> 1) * 256 + ((r1.x & 1) ? 0 : 128) + col];
                unsigned p3 = Pu[(long)(r1.z >> 1) * 256 + ((r1.z & 1) ? 0 : 128) + col];
                unsigned p4 = Pu[(long)(r2.x >> 1) * 256 + ((r2.x & 1) ? 0 : 128) + col];
                unsigned p5 = Pu[(long)(r2.z >> 1) * 256 + ((r2.z & 1) ? 0 : 128) + col];
                unsigned p6 = Pu[(long)(r3.x >> 1) * 256 + ((r3.x & 1) ? 0 : 128) + col];
                unsigned p7 = Pu[(long)(r3.z >> 1) * 256 + ((r3.z & 1) ? 0 : 128) + col];
                ACC(r0.x, r0.y, p0); ACC(r0.z, r0.w, p1);
                ACC(r1.x, r1.y, p2); ACC(r1.z, r1.w, p3);
                ACC(r2.x, r2.y, p4); ACC(r2.z, r2.w, p5);
                ACC(r3.x, r3.y, p6); ACC(r3.z, r3.w, p7);
            } else {             // tail: <=7 incidences, simple scalar-record loop
                for (int k = 0; k < kb; ++k) {
                    int2 rr = srec[i + k];
                    unsigned pv = Pu[(long)(rr.x >> 1) * 256 + ((rr.x & 1) ? 0 : 128) + col];
                    ACC(rr.x, rr.y, pv);
                }
            }
        }
        if (deg > S_SLOTS) {     // rare overflow: walk the global overflow list
            int no = flag[2]; if (no > OVF_CAP) no = OVF_CAP;
            for (int tt = 0; tt < no; ++tt) {
                int4 o = ovf[tt];
                if (o.x == n) {
                    unsigned pv = Pu[(long)(o.y >> 1) * 256 + ((o.y & 1) ? 0 : 128) + col];
                    ACC(o.y, o.z, pv);
                }
            }
        }
        long hrow = (long)n * 256;
        Hcat_u[hrow + col]       = pack4_fp8(accS[0], accS[1], accS[2], accS[3]);
        Hcat_u[hrow + 128 + col] = pack4_fp8(accO[0], accO[1], accO[2], accO[3]);
        if (hw == 0 && lane == 0) { ws_s[n] = wS; ws_o[n] = wO; }
        st = stn; sb = sbn;
    }
}

// ---------- node-level GEMM2 + fused finalize ----------
__global__ __launch_bounds__(512, 4) void gemm2_node(
    const unsigned* __restrict__ Hcat,
    const unsigned char* __restrict__ w2p,
    const float* __restrict__ mbuf,
    const float* __restrict__ ws_s, const float* __restrict__ ws_o,
    const void* __restrict__ objf, const float* __restrict__ b2f,
    void* __restrict__ out, const int* __restrict__ flag)
{
    extern __shared__ char smem[];
    unsigned char* sA = (unsigned char*)smem;     // 32KB frags
    float* sS    = (float*)(smem + 32768);        // [64] each
    float* sSelf = sS + 64;
    float* sInv  = sS + 128;
    float* sWs   = sS + 192;
    float* sWo   = sS + 256;

    const int tid  = threadIdx.x;
    const int wave = tid >> 6;
    const int lane = tid & 63;
    const int l15  = lane & 15;
    const int lq   = lane >> 4;
    const long bs  = (long)blockIdx.x * 64;
    const int isf  = flag[1];

    if (tid < 64) {
        long node = bs + tid; if (node >= O_NODES) node = O_NODES - 1;
        float mm = mbuf[node];
        float mn = fmaxf(mm, 10.0f);
        float S     = __expf(mm - mn);
        float selfw = __expf(10.0f - mn);
        float wss = ws_s[node], wso = ws_o[node];
        sS[tid] = S; sSelf[tid] = selfw; sWs[tid] = wss; sWo[tid] = wso;
        sInv[tid] = 1.0f / (S * (wss + wso) + selfw);
    }

    f32x4 acc[4][2];
    #pragma unroll
    for (int mt = 0; mt < 4; ++mt)
        #pragma unroll
        for (int nt = 0; nt < 2; ++nt)
            acc[mt][nt] = (f32x4){0.f, 0.f, 0.f, 0.f};

    const ulonglong2* bq = (const ulonglong2*)w2p;
    #pragma unroll
    for (int kh = 0; kh < 2; ++kh) {
        #pragma unroll
        for (int it = 0; it < 8; ++it) {
            int q   = it * 512 + tid;
            int m15 = q & 15;
            int mtp = (q >> 4) & 1;
            int h   = (q >> 5) & 1;
            int lqk = (q >> 6) & 3;
            int tk  = (q >> 8) & 15;
            int m   = (h * 2 + mtp) * 16 + m15;
            long node = bs + m; if (node >= O_NODES) node = O_NODES - 1;
            uint2 v = *(const uint2*)(Hcat + node * 256 + kh * 128 + tk * 8 + lqk * 2);
            *(uint2*)(sA + h * 16384 + (tk * 64 + lqk * 16 + m15) * 16 + mtp * 8) = v;
        }
        __syncthreads();
        #pragma unroll 2
        for (int tk = 0; tk < 16; ++tk) {
            int kt = kh * 16 + tk;
            ulonglong2 av01 = *(const ulonglong2*)(sA + tk * 1024 + lane * 16);
            ulonglong2 av23 = *(const ulonglong2*)(sA + 16384 + tk * 1024 + lane * 16);
            ulonglong2 b    = bq[(kt * 8 + wave) * 64 + lane];
            long a0 = (long)av01.x, a1 = (long)av01.y;
            long a2 = (long)av23.x, a3 = (long)av23.y;
            acc[0][0] = mfma_fp8(a0, (long)b.x, acc[0][0]);
            acc[1][0] = mfma_fp8(a1, (long)b.x, acc[1][0]);
            acc[2][0] = mfma_fp8(a2, (long)b.x, acc[2][0]);
            acc[3][0] = mfma_fp8(a3, (long)b.x, acc[3][0]);
            acc[0][1] = mfma_fp8(a0, (long)b.y, acc[0][1]);
            acc[1][1] = mfma_fp8(a1, (long)b.y, acc[1][1]);
            acc[2][1] = mfma_fp8(a2, (long)b.y, acc[2][1]);
            acc[3][1] = mfma_fp8(a3, (long)b.y, acc[3][1]);
        }
        __syncthreads();
    }

    // fused finalize epilogue
    #pragma unroll
    for (int nt = 0; nt < 2; ++nt) {
        int c = wave * 32 + nt * 16 + l15;
        float b2c = b2f[c];
        float b2d = b2f[256 + c];
        #pragma unroll
        for (int mt = 0; mt < 4; ++mt) {
            #pragma unroll
            for (int r = 0; r < 4; ++r) {
                int row = mt * 16 + lq * 4 + r;
                long node = bs + row;
                if (node < O_NODES) {
                    float o = load_f(objf, node * 256 + c, isf);
                    float val = (sS[row] * (acc[mt][nt][r] + sWs[row] * b2c + sWo[row] * b2d)
                                 + sSelf[row] * o) * sInv[row];
                    if (isf) ((float*)out)[node * 256 + c] = val;
                    else     ((unsigned short*)out)[node * 256 + c] = f2bf(val);
                }
            }
        }
    }
}

extern "C" void kernel_launch(void* const* d_in, const int* in_sizes, int n_in,
                              void* d_out, int out_size, void* d_ws, size_t ws_size,
                              hipStream_t stream) {
    const void* objf  = d_in[0];
    const int*  pairs = (const int*)d_in[1];
    const void* conf  = d_in[2];
    const void* W1    = d_in[3];
    const void* b1    = d_in[4];
    const void* W2    = d_in[5];
    const void* b2    = d_in[6];

    char* ws = (char*)d_ws;
    // layout (bytes):
    //   0         count   200000
    //   200000    mbuf    200000
    //   400000    flag    64       (flag[2] = overflow counter)
    //   400064    ovf     65536    (int4 x 4096)
    //   465600    w1p     262144
    //   727744    w2p     262144
    //   989888    ws_s    200000
    //   1189888   ws_o    200000
    //   1389888   b1f     2048
    //   1391936   b2f     2048
    //   1393984   inc2    12800000 (int2 slots [50000][32])
    //   14193984  P       51200000 (fp8 [50k][1024])
    //   65393984  Hcat    51200000
    //   end = 116,593,984  (< 118,124,352 proven available)
    int*   count   = (int*)  ws;
    float* mbuf    = (float*)(ws + 200000);
    int*   flag    = (int*)  (ws + 400000);
    int4*  ovf     = (int4*) (ws + 400064);
    unsigned char* w1p = (unsigned char*)(ws + 465600);
    unsigned char* w2p = (unsigned char*)(ws + 727744);
    float* wss     = (float*)(ws + 989888);
    float* wso     = (float*)(ws + 1189888);
    float* b1f     = (float*)(ws + 1389888);
    float* b2f     = (float*)(ws + 1391936);
    int2*  inc2    = (int2*) (ws + 1393984);
    unsigned char* P     = (unsigned char*)(ws + 14193984);
    unsigned char* Hcat  = (unsigned char*)(ws + 65393984);

    hipMemsetAsync(count, 0, 400064, stream);   // count + mbuf(0) + flag(incl. ovf counter)

    mega_setup<<<MEGA_B + MEGA_C + 2, 256, 0, stream>>>(
        objf, pairs, conf, W1, W2, b1, b2, w1p, w2p, b1f, b2f,
        mbuf, count, flag, inc2, ovf);

    gemm1_node<<<2 * ((O_NODES + 63) / 64), 512, 33792, stream>>>(objf, w1p, P);

    node_accum<<<O_NODES / 16, 256, 0, stream>>>(
        (const unsigned*)P, inc2, count, mbuf, flag, ovf, (const float4*)b1f,
        (unsigned*)Hcat, wss, wso);

    gemm2_node<<<(O_NODES + 63) / 64, 512, 34048, stream>>>(
        (const unsigned*)Hcat, w2p, mbuf, wss, wso, objf, b2f, d_out, flag);
}